// Round 13
// baseline (437.598 us; speedup 1.0000x reference)
//
#include <hip/hip_runtime.h>
#include <math.h>

// ------------------------------------------------------------------
// R13 = R12 with enc_kernel at 2 batches/block (grid 512, 64KB LDS,
// 2 blocks/CU): doubles MFMA work per weight-load latency chain and
// halves per-batch weight traffic. Iter = R12/R6 verbatim.
// 8 dispatches. B=1024, D=256, tok=64, slots=8, iters=5.
// ws (u16): W:0..851968  ks:1<<20  vt:+16M  ping f32 / sraw / lnq after.
// ------------------------------------------------------------------

typedef __attribute__((ext_vector_type(8))) short short8;
typedef __attribute__((ext_vector_type(4))) float f32x4;
typedef unsigned long long ull;

__device__ __forceinline__ unsigned short f2bf(float f) {
    union { float f; unsigned u; } x; x.f = f;
    unsigned r = x.u + 0x7fffu + ((x.u >> 16) & 1u);
    return (unsigned short)(r >> 16);
}
__device__ __forceinline__ float bf2f(unsigned short h) {
    union { unsigned u; float f; } x; x.u = ((unsigned)h) << 16;
    return x.f;
}
__device__ __forceinline__ float sigmoidf_(float x) { return 1.f / (1.f + expf(-x)); }
__device__ __forceinline__ ull pack4(float a, float b, float c, float d) {
    return (ull)f2bf(a) | ((ull)f2bf(b) << 16) | ((ull)f2bf(c) << 32) | ((ull)f2bf(d) << 48);
}
__device__ __forceinline__ short8 afrag256(const unsigned short* buf, int row, int k) {
    return *(const short8*)(buf + row * 256 + (k ^ ((row & 7) << 3)));
}
__device__ __forceinline__ short8 afrag64(const unsigned short* buf, int row, int k) {
    return *(const short8*)(buf + row * 64 + (k ^ ((row & 7) << 3)));
}

// ---------------- weight preconvert (verified) ----------------
__global__ void convert_weights(
    const float* __restrict__ f1W, const float* __restrict__ f2W,
    const float* __restrict__ kW,  const float* __restrict__ vW,
    const float* __restrict__ qW,  const float* __restrict__ m1W,
    const float* __restrict__ m2W, const float* __restrict__ gih,
    const float* __restrict__ ghh, unsigned short* __restrict__ out)
{
    int id = blockIdx.x * 512 + threadIdx.x;
    if (id < 7 * 65536) {
        int mi = id >> 16, e = id & 65535;
        int k = e >> 8, n = e & 255;
        const float* src = mi == 0 ? f1W : mi == 1 ? f2W : mi == 2 ? kW :
                           mi == 3 ? vW  : mi == 4 ? qW  : mi == 5 ? m1W : m2W;
        out[mi * 65536 + n * 256 + k] = f2bf(src[e]);
    } else if (id < 851968) {
        int e = id - 7 * 65536;
        const float* src = e < 196608 ? gih : ghh;
        int ee = e < 196608 ? e : e - 196608;
        out[458752 + e] = f2bf(src[ee]);
    }
}

// ---------------- slot init (verified) ----------------
__launch_bounds__(512)
__global__ void slot_init(const float* __restrict__ mu, const float* __restrict__ sig,
                          const float* __restrict__ noise,
                          const float* __restrict__ nsw, const float* __restrict__ nsb,
                          float* __restrict__ ping, unsigned short* __restrict__ sraw,
                          unsigned short* __restrict__ lnq)
{
    const int t = threadIdx.x, lane = t & 63, wave = t >> 6;
    const int row = blockIdx.x * 8 + wave;
    const int c = lane * 4;
    float4 n4 = *(const float4*)(noise + (size_t)row * 256 + c);
    float4 m4 = *(const float4*)(mu + c);
    float4 g4 = *(const float4*)(sig + c);
    float v0 = m4.x + expf(0.5f * g4.x) * n4.x;
    float v1 = m4.y + expf(0.5f * g4.y) * n4.y;
    float v2 = m4.z + expf(0.5f * g4.z) * n4.z;
    float v3 = m4.w + expf(0.5f * g4.w) * n4.w;
    float s1 = v0 + v1 + v2 + v3;
    float s2 = v0 * v0 + v1 * v1 + v2 * v2 + v3 * v3;
    #pragma unroll
    for (int m = 32; m >= 1; m >>= 1) { s1 += __shfl_xor(s1, m); s2 += __shfl_xor(s2, m); }
    float mu_ = s1 * (1.f / 256.f);
    float rs_ = rsqrtf(s2 * (1.f / 256.f) - mu_ * mu_ + 1e-5f);
    float4 w4 = *(const float4*)(nsw + c);
    float4 b4 = *(const float4*)(nsb + c);
    *(float4*)(ping + (size_t)row * 256 + c) = make_float4(v0, v1, v2, v3);
    *(ull*)(sraw + (size_t)row * 256 + c) = pack4(v0, v1, v2, v3);
    *(ull*)(lnq + (size_t)row * 256 + c) = pack4(
        (v0 - mu_) * rs_ * w4.x + b4.x, (v1 - mu_) * rs_ * w4.y + b4.y,
        (v2 - mu_) * rs_ * w4.z + b4.z, (v3 - mu_) * rs_ * w4.w + b4.w);
}

// ---------------- enc: pos + enLN + f1 + f2 + niLN + K + V (2 batch/blk) --
__launch_bounds__(512)
__global__ void enc_kernel(const float* __restrict__ g_in,
                           const float* __restrict__ g_posW, const float* __restrict__ g_posb,
                           const float* __restrict__ g_enw,  const float* __restrict__ g_enb,
                           const unsigned short* __restrict__ f1t, const float* __restrict__ f1b,
                           const unsigned short* __restrict__ f2t, const float* __restrict__ f2b,
                           const float* __restrict__ niw, const float* __restrict__ nib,
                           const unsigned short* __restrict__ kt,  const float* __restrict__ kb,
                           const unsigned short* __restrict__ vwt, const float* __restrict__ vb,
                           unsigned short* __restrict__ ks, unsigned short* __restrict__ vt)
{
    __shared__ unsigned short xs[128 * 256];     // 2 batches, 64 KB
    __shared__ float red[32];
    const int b0 = blockIdx.x * 2;
    const int t = threadIdx.x, lane = t & 63, wave = t >> 6;
    const int lr = lane & 15, lk = (lane >> 4) * 8, mr = (lane >> 4) * 4;
    const int wc = wave * 32;

    // ---- phase A: load + pos embed + per-batch stats (verified body x2) ----
    {
        float ps[2] = {0.f, 0.f}, pq[2] = {0.f, 0.f};
        for (int i = 0; i < 16; ++i) {
            int bb = i >> 3;
            int idx4 = (i & 7) * 512 + t;
            int d = idx4 >> 4;
            int r0 = (idx4 & 15) << 2;
            float4 v = ((const float4*)(g_in + (size_t)(b0 + bb) * 16384))[idx4];
            float pw0 = g_posW[d], pw1 = g_posW[256 + d], pw2 = g_posW[512 + d], pw3 = g_posW[768 + d];
            float pb = g_posb[d];
            float vals[4] = {v.x, v.y, v.z, v.w};
            #pragma unroll
            for (int q = 0; q < 4; ++q) {
                int r = r0 + q;
                float fh = (float)(r >> 3) * (1.f / 7.f);
                float fw = (float)(r & 7) * (1.f / 7.f);
                float x = vals[q] + fh * pw0 + fw * pw1 + (1.f - fh) * pw2 + (1.f - fw) * pw3 + pb;
                xs[bb * 16384 + r * 256 + (d ^ ((r & 7) << 3))] = f2bf(x);
                ps[bb] += x; pq[bb] += x * x;
            }
        }
        #pragma unroll
        for (int m = 32; m >= 1; m >>= 1) {
            ps[0] += __shfl_xor(ps[0], m); pq[0] += __shfl_xor(pq[0], m);
            ps[1] += __shfl_xor(ps[1], m); pq[1] += __shfl_xor(pq[1], m);
        }
        if (lane == 0) {
            red[wave] = ps[0];      red[8 + wave] = pq[0];
            red[16 + wave] = ps[1]; red[24 + wave] = pq[1];
        }
    }
    __syncthreads();
    // ---- per-batch global enLN in LDS (verified body x2) ----
    {
        #pragma unroll
        for (int bb = 0; bb < 2; ++bb) {
            float tsum = 0.f, tsq = 0.f;
            #pragma unroll
            for (int w2 = 0; w2 < 8; ++w2) { tsum += red[bb * 16 + w2]; tsq += red[bb * 16 + 8 + w2]; }
            float mu = tsum * (1.f / 16384.f);
            float rs = rsqrtf(tsq * (1.f / 16384.f) - mu * mu + 1e-5f);
            int row = t >> 3, c0 = (t & 7) * 32;
            for (int j = 0; j < 8; ++j) {
                int c = c0 + j * 4;
                ull* p = (ull*)(xs + bb * 16384 + row * 256 + (c ^ ((row & 7) << 3)));
                ull pk = *p;
                float4 w4 = *(const float4*)&g_enw[row * 256 + c];
                float4 b4 = *(const float4*)&g_enb[row * 256 + c];
                float v0 = (bf2f((unsigned short)pk)         - mu) * rs * w4.x + b4.x;
                float v1 = (bf2f((unsigned short)(pk >> 16)) - mu) * rs * w4.y + b4.y;
                float v2 = (bf2f((unsigned short)(pk >> 32)) - mu) * rs * w4.z + b4.z;
                float v3 = (bf2f((unsigned short)(pk >> 48)) - mu) * rs * w4.w + b4.w;
                *p = pack4(v0, v1, v2, v3);
            }
        }
    }
    __syncthreads();

    // ---- phase B: f1(relu) over 8 M-tiles, reg-staged back into xs ----
    {
        f32x4 acc[8][2];
        short8 w0[8], w1[8];
        const unsigned short* wp0 = f1t + (size_t)(wc + lr) * 256 + lk;
        const unsigned short* wp1 = f1t + (size_t)(wc + 16 + lr) * 256 + lk;
        #pragma unroll
        for (int kk = 0; kk < 8; ++kk) {
            w0[kk] = *(const short8*)(wp0 + kk * 32);
            w1[kk] = *(const short8*)(wp1 + kk * 32);
        }
        #pragma unroll
        for (int mt = 0; mt < 8; ++mt) {
            acc[mt][0] = (f32x4){0.f,0.f,0.f,0.f};
            acc[mt][1] = (f32x4){0.f,0.f,0.f,0.f};
            short8 a[8];
            #pragma unroll
            for (int kk = 0; kk < 8; ++kk) a[kk] = afrag256(xs, mt * 16 + lr, kk * 32 + lk);
            #pragma unroll
            for (int kk = 0; kk < 8; ++kk) {
                acc[mt][0] = __builtin_amdgcn_mfma_f32_16x16x32_bf16(a[kk], w0[kk], acc[mt][0], 0, 0, 0);
                acc[mt][1] = __builtin_amdgcn_mfma_f32_16x16x32_bf16(a[kk], w1[kk], acc[mt][1], 0, 0, 0);
            }
        }
        __syncthreads();
        const float b0f = f1b[wc + lr], b1f = f1b[wc + 16 + lr];
        #pragma unroll
        for (int mt = 0; mt < 8; ++mt)
            #pragma unroll
            for (int r = 0; r < 4; ++r) {
                int lrow = mt * 16 + mr + r;
                xs[lrow * 256 + ((wc + lr)      ^ ((lrow & 7) << 3))] = f2bf(fmaxf(acc[mt][0][r] + b0f, 0.f));
                xs[lrow * 256 + ((wc + 16 + lr) ^ ((lrow & 7) << 3))] = f2bf(fmaxf(acc[mt][1][r] + b1f, 0.f));
            }
    }
    __syncthreads();

    // ---- phase C: f2(relu) over 8 M-tiles, reg-staged back into xs ----
    {
        f32x4 acc[8][2];
        short8 w0[8], w1[8];
        const unsigned short* wp0 = f2t + (size_t)(wc + lr) * 256 + lk;
        const unsigned short* wp1 = f2t + (size_t)(wc + 16 + lr) * 256 + lk;
        #pragma unroll
        for (int kk = 0; kk < 8; ++kk) {
            w0[kk] = *(const short8*)(wp0 + kk * 32);
            w1[kk] = *(const short8*)(wp1 + kk * 32);
        }
        #pragma unroll
        for (int mt = 0; mt < 8; ++mt) {
            acc[mt][0] = (f32x4){0.f,0.f,0.f,0.f};
            acc[mt][1] = (f32x4){0.f,0.f,0.f,0.f};
            short8 a[8];
            #pragma unroll
            for (int kk = 0; kk < 8; ++kk) a[kk] = afrag256(xs, mt * 16 + lr, kk * 32 + lk);
            #pragma unroll
            for (int kk = 0; kk < 8; ++kk) {
                acc[mt][0] = __builtin_amdgcn_mfma_f32_16x16x32_bf16(a[kk], w0[kk], acc[mt][0], 0, 0, 0);
                acc[mt][1] = __builtin_amdgcn_mfma_f32_16x16x32_bf16(a[kk], w1[kk], acc[mt][1], 0, 0, 0);
            }
        }
        __syncthreads();
        const float b0f = f2b[wc + lr], b1f = f2b[wc + 16 + lr];
        #pragma unroll
        for (int mt = 0; mt < 8; ++mt)
            #pragma unroll
            for (int r = 0; r < 4; ++r) {
                int lrow = mt * 16 + mr + r;
                xs[lrow * 256 + ((wc + lr)      ^ ((lrow & 7) << 3))] = f2bf(fmaxf(acc[mt][0][r] + b0f, 0.f));
                xs[lrow * 256 + ((wc + 16 + lr) ^ ((lrow & 7) << 3))] = f2bf(fmaxf(acc[mt][1][r] + b1f, 0.f));
            }
    }
    __syncthreads();

    // ---- phase D: per-token niLN in place (16 rows/wave) ----
    {
        const float4 w4 = *(const float4*)(niw + lane * 4);
        const float4 b4 = *(const float4*)(nib + lane * 4);
        for (int rr = 0; rr < 16; ++rr) {
            int row = wave * 16 + rr;
            ull* p = (ull*)(xs + row * 256 + ((lane * 4) ^ ((row & 7) << 3)));
            ull pk = *p;
            float v0 = bf2f((unsigned short)pk),         v1 = bf2f((unsigned short)(pk >> 16));
            float v2 = bf2f((unsigned short)(pk >> 32)), v3 = bf2f((unsigned short)(pk >> 48));
            float s1 = v0 + v1 + v2 + v3;
            float s2 = v0 * v0 + v1 * v1 + v2 * v2 + v3 * v3;
            #pragma unroll
            for (int m = 32; m >= 1; m >>= 1) { s1 += __shfl_xor(s1, m); s2 += __shfl_xor(s2, m); }
            float mu_ = s1 * (1.f / 256.f);
            float rs_ = rsqrtf(s2 * (1.f / 256.f) - mu_ * mu_ + 1e-5f);
            *p = pack4((v0 - mu_) * rs_ * w4.x + b4.x, (v1 - mu_) * rs_ * w4.y + b4.y,
                       (v2 - mu_) * rs_ * w4.z + b4.z, (v3 - mu_) * rs_ * w4.w + b4.w);
        }
    }
    __syncthreads();

    // ---- phase E: K GEMM over 8 M-tiles -> ks ----
    {
        short8 w0[8], w1[8];
        const unsigned short* wp0 = kt + (size_t)(wc + lr) * 256 + lk;
        const unsigned short* wp1 = kt + (size_t)(wc + 16 + lr) * 256 + lk;
        #pragma unroll
        for (int kk = 0; kk < 8; ++kk) {
            w0[kk] = *(const short8*)(wp0 + kk * 32);
            w1[kk] = *(const short8*)(wp1 + kk * 32);
        }
        const float b0f = kb[wc + lr], b1f = kb[wc + 16 + lr];
        for (int mt = 0; mt < 8; ++mt) {
            short8 a[8];
            #pragma unroll
            for (int kk = 0; kk < 8; ++kk) a[kk] = afrag256(xs, mt * 16 + lr, kk * 32 + lk);
            f32x4 a0 = (f32x4){0.f,0.f,0.f,0.f}, a1 = (f32x4){0.f,0.f,0.f,0.f};
            #pragma unroll
            for (int kk = 0; kk < 8; ++kk) {
                a0 = __builtin_amdgcn_mfma_f32_16x16x32_bf16(a[kk], w0[kk], a0, 0, 0, 0);
                a1 = __builtin_amdgcn_mfma_f32_16x16x32_bf16(a[kk], w1[kk], a1, 0, 0, 0);
            }
            #pragma unroll
            for (int r = 0; r < 4; ++r) {
                size_t row = (size_t)(b0 + (mt >> 2)) * 64 + (mt & 3) * 16 + mr + r;
                ks[row * 256 + wc + lr]      = f2bf(a0[r] + b0f);
                ks[row * 256 + wc + 16 + lr] = f2bf(a1[r] + b1f);
            }
        }
    }
    // ---- phase F: V GEMM over 8 M-tiles -> vt ----
    {
        short8 w0[8], w1[8];
        const unsigned short* wp0 = vwt + (size_t)(wc + lr) * 256 + lk;
        const unsigned short* wp1 = vwt + (size_t)(wc + 16 + lr) * 256 + lk;
        #pragma unroll
        for (int kk = 0; kk < 8; ++kk) {
            w0[kk] = *(const short8*)(wp0 + kk * 32);
            w1[kk] = *(const short8*)(wp1 + kk * 32);
        }
        const float b0f = vb[wc + lr], b1f = vb[wc + 16 + lr];
        for (int mt = 0; mt < 8; ++mt) {
            short8 a[8];
            #pragma unroll
            for (int kk = 0; kk < 8; ++kk) a[kk] = afrag256(xs, mt * 16 + lr, kk * 32 + lk);
            f32x4 a0 = (f32x4){0.f,0.f,0.f,0.f}, a1 = (f32x4){0.f,0.f,0.f,0.f};
            #pragma unroll
            for (int kk = 0; kk < 8; ++kk) {
                a0 = __builtin_amdgcn_mfma_f32_16x16x32_bf16(a[kk], w0[kk], a0, 0, 0, 0);
                a1 = __builtin_amdgcn_mfma_f32_16x16x32_bf16(a[kk], w1[kk], a1, 0, 0, 0);
            }
            int bidx = b0 + (mt >> 2);
            int t0 = (mt & 3) * 16 + mr;
            *(ull*)(vt + (size_t)bidx * 16384 + (size_t)(wc + lr) * 64 + t0) =
                pack4(a0[0] + b0f, a0[1] + b0f, a0[2] + b0f, a0[3] + b0f);
            *(ull*)(vt + (size_t)bidx * 16384 + (size_t)(wc + 16 + lr) * 64 + t0) =
                pack4(a1[0] + b1f, a1[1] + b1f, a1[2] + b1f, a1[3] + b1f);
        }
    }
}

// ---------------- iter: R12/R6 verbatim ----------------
__launch_bounds__(512)
__global__ void iter_kernel(
    const unsigned short* __restrict__ Kb, const unsigned short* __restrict__ Vtb,
    const unsigned short* __restrict__ qt,
    const unsigned short* __restrict__ gihb, const unsigned short* __restrict__ ghhb,
    const unsigned short* __restrict__ m1t,  const unsigned short* __restrict__ m2t,
    const float* __restrict__ qb,  const float* __restrict__ bih, const float* __restrict__ bhh,
    const float* __restrict__ pfw, const float* __restrict__ pfb,
    const float* __restrict__ m1b, const float* __restrict__ m2b,
    const float* __restrict__ nsw, const float* __restrict__ nsb,
    float* __restrict__ ping, unsigned short* __restrict__ sraw,
    unsigned short* __restrict__ lnq,
    float* __restrict__ outf, int last)
{
    __shared__ unsigned short SA[32 * 256];
    __shared__ unsigned short SS[32 * 256];
    __shared__ unsigned short QP[4][16 * 256];
    __shared__ unsigned short AT[4][16 * 64];
    __shared__ unsigned short US[32 * 256];
    __shared__ float AF[4][8][72];
    __shared__ float HL[32][256];

    const int t = threadIdx.x, lane = t & 63, wave = t >> 6;
    const int m0 = blockIdx.x * 32;
    const int b0 = blockIdx.x * 4;
    const int lr = lane & 15, lk = (lane >> 4) * 8, mr = (lane >> 4) * 4;
    const int wc = wave * 32;

    for (int i = 0; i < 4; ++i) {
        int id = t + 512 * i;
        int row = id >> 6, c4 = (id & 63) * 4;
        size_t g = ((size_t)m0 + row) * 256 + c4;
        int sw = c4 ^ ((row & 7) << 3);
        *(ull*)(SA + row * 256 + sw) = *(const ull*)(lnq + g);
        *(ull*)(SS + row * 256 + sw) = *(const ull*)(sraw + g);
    }
    for (int i = t; i < 2048; i += 512) {
        int bb = i >> 9, rem = i & 511;
        int row = 8 + (rem >> 6), c4 = (rem & 63) * 4;
        *(ull*)(&QP[bb][row * 256 + c4]) = 0;
    }
    for (int i = t; i < 1024; i += 512) ((ull*)AT)[i] = 0;
    __syncthreads();

    // phase 1: q
    {
        short8 w0[8], w1[8];
        const unsigned short* wp0 = qt + (size_t)(wc + lr) * 256 + lk;
        const unsigned short* wp1 = qt + (size_t)(wc + 16 + lr) * 256 + lk;
        #pragma unroll
        for (int kk = 0; kk < 8; ++kk) {
            w0[kk] = *(const short8*)(wp0 + kk * 32);
            w1[kk] = *(const short8*)(wp1 + kk * 32);
        }
        const float bq0 = qb[wc + lr], bq1 = qb[wc + 16 + lr];
        #pragma unroll
        for (int mt = 0; mt < 2; ++mt) {
            short8 a[8];
            #pragma unroll
            for (int kk = 0; kk < 8; ++kk) a[kk] = afrag256(SA, mt * 16 + lr, kk * 32 + lk);
            f32x4 a0 = (f32x4){0.f,0.f,0.f,0.f}, a1 = (f32x4){0.f,0.f,0.f,0.f};
            #pragma unroll
            for (int kk = 0; kk < 8; ++kk) {
                a0 = __builtin_amdgcn_mfma_f32_16x16x32_bf16(a[kk], w0[kk], a0, 0, 0, 0);
                a1 = __builtin_amdgcn_mfma_f32_16x16x32_bf16(a[kk], w1[kk], a1, 0, 0, 0);
            }
            #pragma unroll
            for (int r = 0; r < 4; ++r) {
                int row = mt * 16 + mr + r;
                int bb = row >> 3, sr = row & 7;
                QP[bb][sr * 256 + ((wc + lr)      ^ (sr << 3))] = f2bf(a0[r] + bq0);
                QP[bb][sr * 256 + ((wc + 16 + lr) ^ (sr << 3))] = f2bf(a1[r] + bq1);
            }
        }
    }
    __syncthreads();

    // phase 2: dots
    {
        const int bb = wave >> 1, th = wave & 1;
        const int b = b0 + bb;
        short8 af[8];
        #pragma unroll
        for (int kk = 0; kk < 8; ++kk) af[kk] = afrag256(QP[bb], lr, kk * 32 + lk);
        #pragma unroll
        for (int tf = 0; tf < 2; ++tf) {
            int n0 = th * 32 + tf * 16;
            f32x4 acc = (f32x4){0.f,0.f,0.f,0.f};
            const unsigned short* kp = Kb + ((size_t)b * 64 + n0 + lr) * 256 + lk;
            #pragma unroll
            for (int kk = 0; kk < 8; ++kk)
                acc = __builtin_amdgcn_mfma_f32_16x16x32_bf16(af[kk], *(const short8*)(kp + kk * 32), acc, 0, 0, 0);
            #pragma unroll
            for (int r = 0; r < 4; ++r)
                if (mr + r < 8) AF[bb][mr + r][n0 + lr] = acc[r] * 0.0625f;
        }
    }
    __syncthreads();

    // phase 3: softmax over slots + eps
    if (t < 256) {
        int b2 = t >> 6, tok = t & 63;
        float mx = AF[b2][0][tok];
        #pragma unroll
        for (int s = 1; s < 8; ++s) mx = fmaxf(mx, AF[b2][s][tok]);
        float e[8], den = 0.f;
        #pragma unroll
        for (int s = 0; s < 8; ++s) { e[s] = expf(AF[b2][s][tok] - mx); den += e[s]; }
        float inv = 1.f / den;
        #pragma unroll
        for (int s = 0; s < 8; ++s) AF[b2][s][tok] = e[s] * inv + 1e-8f;
    }
    __syncthreads();

    // phase 4: renormalize over tokens -> AT
    #pragma unroll
    for (int j = 0; j < 4; ++j) {
        int row = wave * 4 + j;
        int bb = row >> 3, sr = row & 7;
        float v = AF[bb][sr][lane];
        float ssum = v;
        #pragma unroll
        for (int m = 32; m >= 1; m >>= 1) ssum += __shfl_xor(ssum, m);
        AT[bb][sr * 64 + (lane ^ (sr << 3))] = f2bf(v / ssum);
    }
    __syncthreads();

    // phase 5: updates = attn @ V -> US
    {
        const int bb = wave >> 1, ch = wave & 1;
        const int b = b0 + bb;
        short8 a0 = afrag64(AT[bb], lr, lk);
        short8 a1 = afrag64(AT[bb], lr, 32 + lk);
        #pragma unroll
        for (int cf = 0; cf < 8; ++cf) {
            int col = ch * 128 + cf * 16 + lr;
            const unsigned short* vp = Vtb + (size_t)b * 16384 + (size_t)col * 64;
            f32x4 acc = (f32x4){0.f,0.f,0.f,0.f};
            acc = __builtin_amdgcn_mfma_f32_16x16x32_bf16(a0, *(const short8*)(vp + lk), acc, 0, 0, 0);
            acc = __builtin_amdgcn_mfma_f32_16x16x32_bf16(a1, *(const short8*)(vp + 32 + lk), acc, 0, 0, 0);
            #pragma unroll
            for (int r = 0; r < 4; ++r)
                if (mr + r < 8) {
                    int row = bb * 8 + mr + r;
                    US[row * 256 + (col ^ ((row & 7) << 3))] = f2bf(acc[r]);
                }
        }
    }
    __syncthreads();

    // phase 6: GRU -> HL; pf-LN -> SA
    {
        f32x4 aR[2][2], aZ[2][2], aN[2][2], aH[2][2];
        #pragma unroll
        for (int cf = 0; cf < 2; ++cf)
            #pragma unroll
            for (int m = 0; m < 2; ++m) {
                aR[cf][m] = (f32x4){0.f,0.f,0.f,0.f}; aZ[cf][m] = (f32x4){0.f,0.f,0.f,0.f};
                aN[cf][m] = (f32x4){0.f,0.f,0.f,0.f}; aH[cf][m] = (f32x4){0.f,0.f,0.f,0.f};
            }
        #pragma unroll
        for (int g = 0; g < 3; ++g) {
            #pragma unroll
            for (int cf = 0; cf < 2; ++cf) {
                int col = wc + cf * 16 + lr;
                const unsigned short* px = gihb + (size_t)(g * 256 + col) * 256 + lk;
                const unsigned short* ph = ghhb + (size_t)(g * 256 + col) * 256 + lk;
                short8 wx[8], wh[8];
                #pragma unroll
                for (int kk = 0; kk < 8; ++kk) {
                    wx[kk] = *(const short8*)(px + kk * 32);
                    wh[kk] = *(const short8*)(ph + kk * 32);
                }
                #pragma unroll
                for (int m = 0; m < 2; ++m) {
                    #pragma unroll
                    for (int kk = 0; kk < 8; ++kk) {
                        short8 u = afrag256(US, m * 16 + lr, kk * 32 + lk);
                        short8 s = afrag256(SS, m * 16 + lr, kk * 32 + lk);
                        if (g == 0) {
                            aR[cf][m] = __builtin_amdgcn_mfma_f32_16x16x32_bf16(u, wx[kk], aR[cf][m], 0, 0, 0);
                            aR[cf][m] = __builtin_amdgcn_mfma_f32_16x16x32_bf16(s, wh[kk], aR[cf][m], 0, 0, 0);
                        } else if (g == 1) {
                            aZ[cf][m] = __builtin_amdgcn_mfma_f32_16x16x32_bf16(u, wx[kk], aZ[cf][m], 0, 0, 0);
                            aZ[cf][m] = __builtin_amdgcn_mfma_f32_16x16x32_bf16(s, wh[kk], aZ[cf][m], 0, 0, 0);
                        } else {
                            aN[cf][m] = __builtin_amdgcn_mfma_f32_16x16x32_bf16(u, wx[kk], aN[cf][m], 0, 0, 0);
                            aH[cf][m] = __builtin_amdgcn_mfma_f32_16x16x32_bf16(s, wh[kk], aH[cf][m], 0, 0, 0);
                        }
                    }
                }
            }
        }
        #pragma unroll
        for (int cf = 0; cf < 2; ++cf) {
            int col = wc + cf * 16 + lr;
            float bR  = bih[col] + bhh[col];
            float bZ  = bih[col + 256] + bhh[col + 256];
            float bXN = bih[col + 512], bHN = bhh[col + 512];
            #pragma unroll
            for (int m = 0; m < 2; ++m)
                #pragma unroll
                for (int r = 0; r < 4; ++r) {
                    int row = m * 16 + mr + r;
                    float prev = ping[((size_t)m0 + row) * 256 + col];
                    float rr = sigmoidf_(aR[cf][m][r] + bR);
                    float zz = sigmoidf_(aZ[cf][m][r] + bZ);
                    float nn = tanhf(aN[cf][m][r] + bXN + rr * (aH[cf][m][r] + bHN));
                    HL[row][col] = (1.f - zz) * nn + zz * prev;
                }
        }
    }
    __syncthreads();
    {
        const float4 w4 = *(const float4*)(pfw + lane * 4);
        const float4 b4 = *(const float4*)(pfb + lane * 4);
        #pragma unroll
        for (int rr = 0; rr < 4; ++rr) {
            int row = wave * 4 + rr;
            float4 v = *(const float4*)&HL[row][lane * 4];
            float s1 = v.x + v.y + v.z + v.w;
            float s2 = v.x * v.x + v.y * v.y + v.z * v.z + v.w * v.w;
            #pragma unroll
            for (int m = 32; m >= 1; m >>= 1) { s1 += __shfl_xor(s1, m); s2 += __shfl_xor(s2, m); }
            float mu_ = s1 * (1.f / 256.f);
            float rs_ = rsqrtf(s2 * (1.f / 256.f) - mu_ * mu_ + 1e-5f);
            *(ull*)(SA + row * 256 + ((lane * 4) ^ ((row & 7) << 3))) = pack4(
                (v.x - mu_) * rs_ * w4.x + b4.x, (v.y - mu_) * rs_ * w4.y + b4.y,
                (v.z - mu_) * rs_ * w4.z + b4.z, (v.w - mu_) * rs_ * w4.w + b4.w);
        }
    }
    __syncthreads();

    // phase 7: m1(relu)
    {
        short8 w0[8], w1[8];
        const unsigned short* wp0 = m1t + (size_t)(wc + lr) * 256 + lk;
        const unsigned short* wp1 = m1t + (size_t)(wc + 16 + lr) * 256 + lk;
        #pragma unroll
        for (int kk = 0; kk < 8; ++kk) {
            w0[kk] = *(const short8*)(wp0 + kk * 32);
            w1[kk] = *(const short8*)(wp1 + kk * 32);
        }
        const float b0f = m1b[wc + lr], b1f = m1b[wc + 16 + lr];
        #pragma unroll
        for (int mt = 0; mt < 2; ++mt) {
            short8 a[8];
            #pragma unroll
            for (int kk = 0; kk < 8; ++kk) a[kk] = afrag256(SA, mt * 16 + lr, kk * 32 + lk);
            f32x4 a0 = (f32x4){0.f,0.f,0.f,0.f}, a1 = (f32x4){0.f,0.f,0.f,0.f};
            #pragma unroll
            for (int kk = 0; kk < 8; ++kk) {
                a0 = __builtin_amdgcn_mfma_f32_16x16x32_bf16(a[kk], w0[kk], a0, 0, 0, 0);
                a1 = __builtin_amdgcn_mfma_f32_16x16x32_bf16(a[kk], w1[kk], a1, 0, 0, 0);
            }
            #pragma unroll
            for (int r = 0; r < 4; ++r) {
                int row = mt * 16 + mr + r;
                US[row * 256 + ((wc + lr)      ^ ((row & 7) << 3))] = f2bf(fmaxf(a0[r] + b0f, 0.f));
                US[row * 256 + ((wc + 16 + lr) ^ ((row & 7) << 3))] = f2bf(fmaxf(a1[r] + b1f, 0.f));
            }
        }
    }
    __syncthreads();

    // phase 8: m2 + residual -> HL
    {
        short8 w0[8], w1[8];
        const unsigned short* wp0 = m2t + (size_t)(wc + lr) * 256 + lk;
        const unsigned short* wp1 = m2t + (size_t)(wc + 16 + lr) * 256 + lk;
        #pragma unroll
        for (int kk = 0; kk < 8; ++kk) {
            w0[kk] = *(const short8*)(wp0 + kk * 32);
            w1[kk] = *(const short8*)(wp1 + kk * 32);
        }
        const float b0f = m2b[wc + lr], b1f = m2b[wc + 16 + lr];
        #pragma unroll
        for (int mt = 0; mt < 2; ++mt) {
            short8 a[8];
            #pragma unroll
            for (int kk = 0; kk < 8; ++kk) a[kk] = afrag256(US, mt * 16 + lr, kk * 32 + lk);
            f32x4 a0 = (f32x4){0.f,0.f,0.f,0.f}, a1 = (f32x4){0.f,0.f,0.f,0.f};
            #pragma unroll
            for (int kk = 0; kk < 8; ++kk) {
                a0 = __builtin_amdgcn_mfma_f32_16x16x32_bf16(a[kk], w0[kk], a0, 0, 0, 0);
                a1 = __builtin_amdgcn_mfma_f32_16x16x32_bf16(a[kk], w1[kk], a1, 0, 0, 0);
            }
            #pragma unroll
            for (int r = 0; r < 4; ++r) {
                int row = mt * 16 + mr + r;
                HL[row][wc + lr]      = a0[r] + b0f + HL[row][wc + lr];
                HL[row][wc + 16 + lr] = a1[r] + b1f + HL[row][wc + 16 + lr];
            }
        }
    }
    __syncthreads();

    // epilogue
    if (last) {
        #pragma unroll
        for (int rr = 0; rr < 4; ++rr) {
            int row = wave * 4 + rr;
            *(float4*)(outf + ((size_t)m0 + row) * 256 + lane * 4) =
                *(const float4*)&HL[row][lane * 4];
        }
    } else {
        const float4 w4 = *(const float4*)(nsw + lane * 4);
        const float4 b4 = *(const float4*)(nsb + lane * 4);
        #pragma unroll
        for (int rr = 0; rr < 4; ++rr) {
            int row = wave * 4 + rr;
            float4 v = *(const float4*)&HL[row][lane * 4];
            float s1 = v.x + v.y + v.z + v.w;
            float s2 = v.x * v.x + v.y * v.y + v.z * v.z + v.w * v.w;
            #pragma unroll
            for (int m = 32; m >= 1; m >>= 1) { s1 += __shfl_xor(s1, m); s2 += __shfl_xor(s2, m); }
            float mu_ = s1 * (1.f / 256.f);
            float rs_ = rsqrtf(s2 * (1.f / 256.f) - mu_ * mu_ + 1e-5f);
            size_t off = ((size_t)m0 + row) * 256 + lane * 4;
            *(float4*)(ping + off) = v;
            *(ull*)(sraw + off) = pack4(v.x, v.y, v.z, v.w);
            *(ull*)(lnq + off) = pack4(
                (v.x - mu_) * rs_ * w4.x + b4.x, (v.y - mu_) * rs_ * w4.y + b4.y,
                (v.z - mu_) * rs_ * w4.z + b4.z, (v.w - mu_) * rs_ * w4.w + b4.w);
        }
    }
}

// ------------------------------------------------------------------
extern "C" void kernel_launch(void* const* d_in, const int* in_sizes, int n_in,
                              void* d_out, int out_size, void* d_ws, size_t ws_size,
                              hipStream_t stream) {
    (void)in_sizes; (void)n_in; (void)ws_size; (void)out_size;
    unsigned short* wsb  = (unsigned short*)d_ws;
    unsigned short* ksb  = wsb + (1u << 20);         // K
    unsigned short* vtb  = ksb + 16777216;           // V^T
    float* ping = (float*)(vtb + 16777216);
    unsigned short* srawb = (unsigned short*)(ping + 2097152);
    unsigned short* lnqb  = srawb + 2097152;

    const unsigned short* f1t  = wsb;
    const unsigned short* f2t  = wsb + 65536;
    const unsigned short* kt   = wsb + 131072;
    const unsigned short* vwt  = wsb + 196608;
    const unsigned short* qt   = wsb + 262144;
    const unsigned short* m1t  = wsb + 327680;
    const unsigned short* m2t  = wsb + 393216;
    const unsigned short* gihb = wsb + 458752;
    const unsigned short* ghhb = wsb + 655360;

    convert_weights<<<dim3(1664), dim3(512), 0, stream>>>(
        (const float*)d_in[6],  (const float*)d_in[8],  (const float*)d_in[14],
        (const float*)d_in[16], (const float*)d_in[12], (const float*)d_in[26],
        (const float*)d_in[28], (const float*)d_in[18], (const float*)d_in[19], wsb);

    enc_kernel<<<dim3(512), dim3(512), 0, stream>>>(
        (const float*)d_in[0], (const float*)d_in[2], (const float*)d_in[3],
        (const float*)d_in[4], (const float*)d_in[5],
        f1t, (const float*)d_in[7],
        f2t, (const float*)d_in[9],
        (const float*)d_in[10], (const float*)d_in[11],
        kt, (const float*)d_in[15], vwt, (const float*)d_in[17],
        ksb, vtb);

    slot_init<<<dim3(1024), dim3(512), 0, stream>>>(
        (const float*)d_in[30], (const float*)d_in[31], (const float*)d_in[1],
        (const float*)d_in[22], (const float*)d_in[23], ping, srawb, lnqb);

    for (int it = 0; it < 5; ++it) {
        iter_kernel<<<dim3(256), dim3(512), 0, stream>>>(
            ksb, vtb, qt, gihb, ghhb, m1t, m2t,
            (const float*)d_in[13], (const float*)d_in[20], (const float*)d_in[21],
            (const float*)d_in[24], (const float*)d_in[25],
            (const float*)d_in[27], (const float*)d_in[29],
            (const float*)d_in[22], (const float*)d_in[23],
            ping, srawb, lnqb,
            (float*)d_out, it == 4 ? 1 : 0);
    }
}

// Round 14
// 407.011 us; speedup vs baseline: 1.0752x; 1.0752x over previous
//
#include <hip/hip_runtime.h>
#include <math.h>

// ------------------------------------------------------------------
// R14 = R12 (best, 416us) with iter LDS compacted to exactly 80KB
// (unpadded QP/AT via predicated A-frag loads + {QP,AF,AT}|HL union)
// -> 2 blocks/CU for cross-block latency overlap at unchanged weight
// traffic. enc reverted to R12's 1-batch/block form.
// 8 dispatches. B=1024, D=256, tok=64, slots=8, iters=5.
// ws (u16): W:0..851968  ks:1<<20  vt:+16M  ping f32 / sraw / lnq after.
// ------------------------------------------------------------------

typedef __attribute__((ext_vector_type(8))) short short8;
typedef __attribute__((ext_vector_type(4))) float f32x4;
typedef unsigned long long ull;

__device__ __forceinline__ unsigned short f2bf(float f) {
    union { float f; unsigned u; } x; x.f = f;
    unsigned r = x.u + 0x7fffu + ((x.u >> 16) & 1u);
    return (unsigned short)(r >> 16);
}
__device__ __forceinline__ float bf2f(unsigned short h) {
    union { unsigned u; float f; } x; x.u = ((unsigned)h) << 16;
    return x.f;
}
__device__ __forceinline__ float sigmoidf_(float x) { return 1.f / (1.f + expf(-x)); }
__device__ __forceinline__ ull pack4(float a, float b, float c, float d) {
    return (ull)f2bf(a) | ((ull)f2bf(b) << 16) | ((ull)f2bf(c) << 32) | ((ull)f2bf(d) << 48);
}
__device__ __forceinline__ short8 afrag256(const unsigned short* buf, int row, int k) {
    return *(const short8*)(buf + row * 256 + (k ^ ((row & 7) << 3)));
}
__device__ __forceinline__ short8 afrag64(const unsigned short* buf, int row, int k) {
    return *(const short8*)(buf + row * 64 + (k ^ ((row & 7) << 3)));
}

// ---------------- weight preconvert (verified) ----------------
__global__ void convert_weights(
    const float* __restrict__ f1W, const float* __restrict__ f2W,
    const float* __restrict__ kW,  const float* __restrict__ vW,
    const float* __restrict__ qW,  const float* __restrict__ m1W,
    const float* __restrict__ m2W, const float* __restrict__ gih,
    const float* __restrict__ ghh, unsigned short* __restrict__ out)
{
    int id = blockIdx.x * 512 + threadIdx.x;
    if (id < 7 * 65536) {
        int mi = id >> 16, e = id & 65535;
        int k = e >> 8, n = e & 255;
        const float* src = mi == 0 ? f1W : mi == 1 ? f2W : mi == 2 ? kW :
                           mi == 3 ? vW  : mi == 4 ? qW  : mi == 5 ? m1W : m2W;
        out[mi * 65536 + n * 256 + k] = f2bf(src[e]);
    } else if (id < 851968) {
        int e = id - 7 * 65536;
        const float* src = e < 196608 ? gih : ghh;
        int ee = e < 196608 ? e : e - 196608;
        out[458752 + e] = f2bf(src[ee]);
    }
}

// ---------------- slot init (verified) ----------------
__launch_bounds__(512)
__global__ void slot_init(const float* __restrict__ mu, const float* __restrict__ sig,
                          const float* __restrict__ noise,
                          const float* __restrict__ nsw, const float* __restrict__ nsb,
                          float* __restrict__ ping, unsigned short* __restrict__ sraw,
                          unsigned short* __restrict__ lnq)
{
    const int t = threadIdx.x, lane = t & 63, wave = t >> 6;
    const int row = blockIdx.x * 8 + wave;
    const int c = lane * 4;
    float4 n4 = *(const float4*)(noise + (size_t)row * 256 + c);
    float4 m4 = *(const float4*)(mu + c);
    float4 g4 = *(const float4*)(sig + c);
    float v0 = m4.x + expf(0.5f * g4.x) * n4.x;
    float v1 = m4.y + expf(0.5f * g4.y) * n4.y;
    float v2 = m4.z + expf(0.5f * g4.z) * n4.z;
    float v3 = m4.w + expf(0.5f * g4.w) * n4.w;
    float s1 = v0 + v1 + v2 + v3;
    float s2 = v0 * v0 + v1 * v1 + v2 * v2 + v3 * v3;
    #pragma unroll
    for (int m = 32; m >= 1; m >>= 1) { s1 += __shfl_xor(s1, m); s2 += __shfl_xor(s2, m); }
    float mu_ = s1 * (1.f / 256.f);
    float rs_ = rsqrtf(s2 * (1.f / 256.f) - mu_ * mu_ + 1e-5f);
    float4 w4 = *(const float4*)(nsw + c);
    float4 b4 = *(const float4*)(nsb + c);
    *(float4*)(ping + (size_t)row * 256 + c) = make_float4(v0, v1, v2, v3);
    *(ull*)(sraw + (size_t)row * 256 + c) = pack4(v0, v1, v2, v3);
    *(ull*)(lnq + (size_t)row * 256 + c) = pack4(
        (v0 - mu_) * rs_ * w4.x + b4.x, (v1 - mu_) * rs_ * w4.y + b4.y,
        (v2 - mu_) * rs_ * w4.z + b4.z, (v3 - mu_) * rs_ * w4.w + b4.w);
}

// ---------------- enc: R12 verbatim (1 batch/block, best measured) -------
__launch_bounds__(512)
__global__ void enc_kernel(const float* __restrict__ g_in,
                           const float* __restrict__ g_posW, const float* __restrict__ g_posb,
                           const float* __restrict__ g_enw,  const float* __restrict__ g_enb,
                           const unsigned short* __restrict__ f1t, const float* __restrict__ f1b,
                           const unsigned short* __restrict__ f2t, const float* __restrict__ f2b,
                           const float* __restrict__ niw, const float* __restrict__ nib,
                           const unsigned short* __restrict__ kt,  const float* __restrict__ kb,
                           const unsigned short* __restrict__ vwt, const float* __restrict__ vb,
                           unsigned short* __restrict__ ks, unsigned short* __restrict__ vt)
{
    __shared__ unsigned short xs[64 * 256];
    __shared__ float red[16];
    const int b = blockIdx.x, t = threadIdx.x, lane = t & 63, wave = t >> 6;
    const int lr = lane & 15, lk = (lane >> 4) * 8, mr = (lane >> 4) * 4;
    const int wc = wave * 32;

    const float* inb = g_in + (size_t)b * 16384;
    float psum = 0.f, psq = 0.f;
    for (int i = 0; i < 8; ++i) {
        int idx4 = i * 512 + t;
        int d = idx4 >> 4;
        int r0 = (idx4 & 15) << 2;
        float4 v = ((const float4*)inb)[idx4];
        float pw0 = g_posW[d], pw1 = g_posW[256 + d], pw2 = g_posW[512 + d], pw3 = g_posW[768 + d];
        float pb = g_posb[d];
        float vals[4] = {v.x, v.y, v.z, v.w};
        #pragma unroll
        for (int q = 0; q < 4; ++q) {
            int r = r0 + q;
            float fh = (float)(r >> 3) * (1.f / 7.f);
            float fw = (float)(r & 7) * (1.f / 7.f);
            float x = vals[q] + fh * pw0 + fw * pw1 + (1.f - fh) * pw2 + (1.f - fw) * pw3 + pb;
            xs[r * 256 + (d ^ ((r & 7) << 3))] = f2bf(x);
            psum += x; psq += x * x;
        }
    }
    #pragma unroll
    for (int m = 32; m >= 1; m >>= 1) { psum += __shfl_xor(psum, m); psq += __shfl_xor(psq, m); }
    if (lane == 0) { red[wave] = psum; red[8 + wave] = psq; }
    __syncthreads();
    {
        float tsum = 0.f, tsq = 0.f;
        #pragma unroll
        for (int w2 = 0; w2 < 8; ++w2) { tsum += red[w2]; tsq += red[8 + w2]; }
        float mu = tsum * (1.f / 16384.f);
        float rs = rsqrtf(tsq * (1.f / 16384.f) - mu * mu + 1e-5f);
        int row = t >> 3, c0 = (t & 7) * 32;
        for (int j = 0; j < 8; ++j) {
            int c = c0 + j * 4;
            ull* p = (ull*)(xs + row * 256 + (c ^ ((row & 7) << 3)));
            ull pk = *p;
            float4 w4 = *(const float4*)&g_enw[row * 256 + c];
            float4 b4 = *(const float4*)&g_enb[row * 256 + c];
            float v0 = (bf2f((unsigned short)pk)         - mu) * rs * w4.x + b4.x;
            float v1 = (bf2f((unsigned short)(pk >> 16)) - mu) * rs * w4.y + b4.y;
            float v2 = (bf2f((unsigned short)(pk >> 32)) - mu) * rs * w4.z + b4.z;
            float v3 = (bf2f((unsigned short)(pk >> 48)) - mu) * rs * w4.w + b4.w;
            *p = pack4(v0, v1, v2, v3);
        }
    }
    __syncthreads();

    // f1(relu) reg-staged back into xs
    {
        f32x4 acc[4][2];
        short8 w0[8], w1[8];
        const unsigned short* wp0 = f1t + (size_t)(wc + lr) * 256 + lk;
        const unsigned short* wp1 = f1t + (size_t)(wc + 16 + lr) * 256 + lk;
        #pragma unroll
        for (int kk = 0; kk < 8; ++kk) {
            w0[kk] = *(const short8*)(wp0 + kk * 32);
            w1[kk] = *(const short8*)(wp1 + kk * 32);
        }
        #pragma unroll
        for (int mt = 0; mt < 4; ++mt) {
            acc[mt][0] = (f32x4){0.f,0.f,0.f,0.f};
            acc[mt][1] = (f32x4){0.f,0.f,0.f,0.f};
            short8 a[8];
            #pragma unroll
            for (int kk = 0; kk < 8; ++kk) a[kk] = afrag256(xs, mt * 16 + lr, kk * 32 + lk);
            #pragma unroll
            for (int kk = 0; kk < 8; ++kk) {
                acc[mt][0] = __builtin_amdgcn_mfma_f32_16x16x32_bf16(a[kk], w0[kk], acc[mt][0], 0, 0, 0);
                acc[mt][1] = __builtin_amdgcn_mfma_f32_16x16x32_bf16(a[kk], w1[kk], acc[mt][1], 0, 0, 0);
            }
        }
        __syncthreads();
        const float b0 = f1b[wc + lr], b1 = f1b[wc + 16 + lr];
        #pragma unroll
        for (int mt = 0; mt < 4; ++mt)
            #pragma unroll
            for (int r = 0; r < 4; ++r) {
                int lrow = mt * 16 + mr + r;
                xs[lrow * 256 + ((wc + lr)      ^ ((lrow & 7) << 3))] = f2bf(fmaxf(acc[mt][0][r] + b0, 0.f));
                xs[lrow * 256 + ((wc + 16 + lr) ^ ((lrow & 7) << 3))] = f2bf(fmaxf(acc[mt][1][r] + b1, 0.f));
            }
    }
    __syncthreads();

    // f2(relu) reg-staged back into xs
    {
        f32x4 acc[4][2];
        short8 w0[8], w1[8];
        const unsigned short* wp0 = f2t + (size_t)(wc + lr) * 256 + lk;
        const unsigned short* wp1 = f2t + (size_t)(wc + 16 + lr) * 256 + lk;
        #pragma unroll
        for (int kk = 0; kk < 8; ++kk) {
            w0[kk] = *(const short8*)(wp0 + kk * 32);
            w1[kk] = *(const short8*)(wp1 + kk * 32);
        }
        #pragma unroll
        for (int mt = 0; mt < 4; ++mt) {
            acc[mt][0] = (f32x4){0.f,0.f,0.f,0.f};
            acc[mt][1] = (f32x4){0.f,0.f,0.f,0.f};
            short8 a[8];
            #pragma unroll
            for (int kk = 0; kk < 8; ++kk) a[kk] = afrag256(xs, mt * 16 + lr, kk * 32 + lk);
            #pragma unroll
            for (int kk = 0; kk < 8; ++kk) {
                acc[mt][0] = __builtin_amdgcn_mfma_f32_16x16x32_bf16(a[kk], w0[kk], acc[mt][0], 0, 0, 0);
                acc[mt][1] = __builtin_amdgcn_mfma_f32_16x16x32_bf16(a[kk], w1[kk], acc[mt][1], 0, 0, 0);
            }
        }
        __syncthreads();
        const float b0 = f2b[wc + lr], b1 = f2b[wc + 16 + lr];
        #pragma unroll
        for (int mt = 0; mt < 4; ++mt)
            #pragma unroll
            for (int r = 0; r < 4; ++r) {
                int lrow = mt * 16 + mr + r;
                xs[lrow * 256 + ((wc + lr)      ^ ((lrow & 7) << 3))] = f2bf(fmaxf(acc[mt][0][r] + b0, 0.f));
                xs[lrow * 256 + ((wc + 16 + lr) ^ ((lrow & 7) << 3))] = f2bf(fmaxf(acc[mt][1][r] + b1, 0.f));
            }
    }
    __syncthreads();

    // niLN in place
    {
        const float4 w4 = *(const float4*)(niw + lane * 4);
        const float4 b4 = *(const float4*)(nib + lane * 4);
        for (int rr = 0; rr < 8; ++rr) {
            int row = wave * 8 + rr;
            ull* p = (ull*)(xs + row * 256 + ((lane * 4) ^ ((row & 7) << 3)));
            ull pk = *p;
            float v0 = bf2f((unsigned short)pk),         v1 = bf2f((unsigned short)(pk >> 16));
            float v2 = bf2f((unsigned short)(pk >> 32)), v3 = bf2f((unsigned short)(pk >> 48));
            float s1 = v0 + v1 + v2 + v3;
            float s2 = v0 * v0 + v1 * v1 + v2 * v2 + v3 * v3;
            #pragma unroll
            for (int m = 32; m >= 1; m >>= 1) { s1 += __shfl_xor(s1, m); s2 += __shfl_xor(s2, m); }
            float mu_ = s1 * (1.f / 256.f);
            float rs_ = rsqrtf(s2 * (1.f / 256.f) - mu_ * mu_ + 1e-5f);
            *p = pack4((v0 - mu_) * rs_ * w4.x + b4.x, (v1 - mu_) * rs_ * w4.y + b4.y,
                       (v2 - mu_) * rs_ * w4.z + b4.z, (v3 - mu_) * rs_ * w4.w + b4.w);
        }
    }
    __syncthreads();

    // K GEMM -> ks
    {
        short8 w0[8], w1[8];
        const unsigned short* wp0 = kt + (size_t)(wc + lr) * 256 + lk;
        const unsigned short* wp1 = kt + (size_t)(wc + 16 + lr) * 256 + lk;
        #pragma unroll
        for (int kk = 0; kk < 8; ++kk) {
            w0[kk] = *(const short8*)(wp0 + kk * 32);
            w1[kk] = *(const short8*)(wp1 + kk * 32);
        }
        const float b0 = kb[wc + lr], b1 = kb[wc + 16 + lr];
        for (int mt = 0; mt < 4; ++mt) {
            short8 a[8];
            #pragma unroll
            for (int kk = 0; kk < 8; ++kk) a[kk] = afrag256(xs, mt * 16 + lr, kk * 32 + lk);
            f32x4 a0 = (f32x4){0.f,0.f,0.f,0.f}, a1 = (f32x4){0.f,0.f,0.f,0.f};
            #pragma unroll
            for (int kk = 0; kk < 8; ++kk) {
                a0 = __builtin_amdgcn_mfma_f32_16x16x32_bf16(a[kk], w0[kk], a0, 0, 0, 0);
                a1 = __builtin_amdgcn_mfma_f32_16x16x32_bf16(a[kk], w1[kk], a1, 0, 0, 0);
            }
            #pragma unroll
            for (int r = 0; r < 4; ++r) {
                size_t row = (size_t)b * 64 + mt * 16 + mr + r;
                ks[row * 256 + wc + lr]      = f2bf(a0[r] + b0);
                ks[row * 256 + wc + 16 + lr] = f2bf(a1[r] + b1);
            }
        }
    }
    // V GEMM -> vt
    {
        short8 w0[8], w1[8];
        const unsigned short* wp0 = vwt + (size_t)(wc + lr) * 256 + lk;
        const unsigned short* wp1 = vwt + (size_t)(wc + 16 + lr) * 256 + lk;
        #pragma unroll
        for (int kk = 0; kk < 8; ++kk) {
            w0[kk] = *(const short8*)(wp0 + kk * 32);
            w1[kk] = *(const short8*)(wp1 + kk * 32);
        }
        const float b0 = vb[wc + lr], b1 = vb[wc + 16 + lr];
        for (int mt = 0; mt < 4; ++mt) {
            short8 a[8];
            #pragma unroll
            for (int kk = 0; kk < 8; ++kk) a[kk] = afrag256(xs, mt * 16 + lr, kk * 32 + lk);
            f32x4 a0 = (f32x4){0.f,0.f,0.f,0.f}, a1 = (f32x4){0.f,0.f,0.f,0.f};
            #pragma unroll
            for (int kk = 0; kk < 8; ++kk) {
                a0 = __builtin_amdgcn_mfma_f32_16x16x32_bf16(a[kk], w0[kk], a0, 0, 0, 0);
                a1 = __builtin_amdgcn_mfma_f32_16x16x32_bf16(a[kk], w1[kk], a1, 0, 0, 0);
            }
            int t0 = mt * 16 + mr;
            *(ull*)(vt + (size_t)b * 16384 + (size_t)(wc + lr) * 64 + t0) =
                pack4(a0[0] + b0, a0[1] + b0, a0[2] + b0, a0[3] + b0);
            *(ull*)(vt + (size_t)b * 16384 + (size_t)(wc + 16 + lr) * 64 + t0) =
                pack4(a1[0] + b1, a1[1] + b1, a1[2] + b1, a1[3] + b1);
        }
    }
}

// ---------------- iter: 80KB-LDS version (2 blocks/CU) -------------------
__launch_bounds__(512)
__global__ void iter_kernel(
    const unsigned short* __restrict__ Kb, const unsigned short* __restrict__ Vtb,
    const unsigned short* __restrict__ qt,
    const unsigned short* __restrict__ gihb, const unsigned short* __restrict__ ghhb,
    const unsigned short* __restrict__ m1t,  const unsigned short* __restrict__ m2t,
    const float* __restrict__ qb,  const float* __restrict__ bih, const float* __restrict__ bhh,
    const float* __restrict__ pfw, const float* __restrict__ pfb,
    const float* __restrict__ m1b, const float* __restrict__ m2b,
    const float* __restrict__ nsw, const float* __restrict__ nsb,
    float* __restrict__ ping, unsigned short* __restrict__ sraw,
    unsigned short* __restrict__ lnq,
    float* __restrict__ outf, int last)
{
    __shared__ unsigned short SA[32 * 256];              // 16 KB
    __shared__ unsigned short SS[32 * 256];              // 16 KB
    __shared__ unsigned short US[32 * 256];              // 16 KB
    // union region (32 KB): phases 1-5 use {QP,AF,AT}; phases 6+ use HL.
    __shared__ __align__(16) unsigned char UN[32768];
    unsigned short* QP = (unsigned short*)UN;                    // [4][8*256] 16384B
    float*          AFb = (float*)(UN + 16384);                  // [4][8][72]  9216B
    unsigned short* ATb = (unsigned short*)(UN + 16384 + 9216);  // [4][8*64]   4096B
    float (*HL)[256] = (float(*)[256])UN;                        // [32][256]  32768B

    const int t = threadIdx.x, lane = t & 63, wave = t >> 6;
    const int m0 = blockIdx.x * 32;
    const int b0 = blockIdx.x * 4;
    const int lr = lane & 15, lk = (lane >> 4) * 8, mr = (lane >> 4) * 4;
    const int wc = wave * 32;
    const short8 z8 = (short8){0,0,0,0,0,0,0,0};

    // ---- stage SA<-lnq, SS<-sraw (no pad zeroing needed anymore) ----
    for (int i = 0; i < 4; ++i) {
        int id = t + 512 * i;
        int row = id >> 6, c4 = (id & 63) * 4;
        size_t g = ((size_t)m0 + row) * 256 + c4;
        int sw = c4 ^ ((row & 7) << 3);
        *(ull*)(SA + row * 256 + sw) = *(const ull*)(lnq + g);
        *(ull*)(SS + row * 256 + sw) = *(const ull*)(sraw + g);
    }
    __syncthreads();

    // ---- phase 1: q = SA @ qt -> QP (unpadded [4][8*256]) ----
    {
        short8 w0[8], w1[8];
        const unsigned short* wp0 = qt + (size_t)(wc + lr) * 256 + lk;
        const unsigned short* wp1 = qt + (size_t)(wc + 16 + lr) * 256 + lk;
        #pragma unroll
        for (int kk = 0; kk < 8; ++kk) {
            w0[kk] = *(const short8*)(wp0 + kk * 32);
            w1[kk] = *(const short8*)(wp1 + kk * 32);
        }
        const float bq0 = qb[wc + lr], bq1 = qb[wc + 16 + lr];
        #pragma unroll
        for (int mt = 0; mt < 2; ++mt) {
            short8 a[8];
            #pragma unroll
            for (int kk = 0; kk < 8; ++kk) a[kk] = afrag256(SA, mt * 16 + lr, kk * 32 + lk);
            f32x4 a0 = (f32x4){0.f,0.f,0.f,0.f}, a1 = (f32x4){0.f,0.f,0.f,0.f};
            #pragma unroll
            for (int kk = 0; kk < 8; ++kk) {
                a0 = __builtin_amdgcn_mfma_f32_16x16x32_bf16(a[kk], w0[kk], a0, 0, 0, 0);
                a1 = __builtin_amdgcn_mfma_f32_16x16x32_bf16(a[kk], w1[kk], a1, 0, 0, 0);
            }
            #pragma unroll
            for (int r = 0; r < 4; ++r) {
                int row = mt * 16 + mr + r;
                int bb = row >> 3, sr = row & 7;
                unsigned short* q = QP + bb * 2048;
                q[sr * 256 + ((wc + lr)      ^ (sr << 3))] = f2bf(a0[r] + bq0);
                q[sr * 256 + ((wc + 16 + lr) ^ (sr << 3))] = f2bf(a1[r] + bq1);
            }
        }
    }
    __syncthreads();

    // ---- phase 2: dots = q @ K^T * scale (predicated A rows) ----
    {
        const int bb = wave >> 1, th = wave & 1;
        const int b = b0 + bb;
        const unsigned short* q = QP + bb * 2048;
        short8 af[8];
        #pragma unroll
        for (int kk = 0; kk < 8; ++kk)
            af[kk] = (lr < 8) ? *(const short8*)(q + lr * 256 + ((kk * 32 + lk) ^ (lr << 3))) : z8;
        #pragma unroll
        for (int tf = 0; tf < 2; ++tf) {
            int n0 = th * 32 + tf * 16;
            f32x4 acc = (f32x4){0.f,0.f,0.f,0.f};
            const unsigned short* kp = Kb + ((size_t)b * 64 + n0 + lr) * 256 + lk;
            #pragma unroll
            for (int kk = 0; kk < 8; ++kk)
                acc = __builtin_amdgcn_mfma_f32_16x16x32_bf16(af[kk], *(const short8*)(kp + kk * 32), acc, 0, 0, 0);
            #pragma unroll
            for (int r = 0; r < 4; ++r)
                if (mr + r < 8) AFb[bb * 576 + (mr + r) * 72 + n0 + lr] = acc[r] * 0.0625f;
        }
    }
    __syncthreads();

    // ---- phase 3: softmax over slots per token + eps ----
    if (t < 256) {
        int b2 = t >> 6, tok = t & 63;
        float* A = AFb + b2 * 576;
        float mx = A[tok];
        #pragma unroll
        for (int s = 1; s < 8; ++s) mx = fmaxf(mx, A[s * 72 + tok]);
        float e[8], den = 0.f;
        #pragma unroll
        for (int s = 0; s < 8; ++s) { e[s] = expf(A[s * 72 + tok] - mx); den += e[s]; }
        float inv = 1.f / den;
        #pragma unroll
        for (int s = 0; s < 8; ++s) A[s * 72 + tok] = e[s] * inv + 1e-8f;
    }
    __syncthreads();

    // ---- phase 4: renormalize over tokens -> AT (unpadded [4][8*64]) ----
    #pragma unroll
    for (int j = 0; j < 4; ++j) {
        int row = wave * 4 + j;
        int bb = row >> 3, sr = row & 7;
        float v = AFb[bb * 576 + sr * 72 + lane];
        float ssum = v;
        #pragma unroll
        for (int m = 32; m >= 1; m >>= 1) ssum += __shfl_xor(ssum, m);
        (ATb + bb * 512)[sr * 64 + (lane ^ (sr << 3))] = f2bf(v / ssum);
    }
    __syncthreads();

    // ---- phase 5: updates = attn @ V -> US (predicated A rows) ----
    {
        const int bb = wave >> 1, ch = wave & 1;
        const int b = b0 + bb;
        const unsigned short* at = ATb + bb * 512;
        short8 a0 = (lr < 8) ? *(const short8*)(at + lr * 64 + ((lk)      ^ (lr << 3))) : z8;
        short8 a1 = (lr < 8) ? *(const short8*)(at + lr * 64 + ((32 + lk) ^ (lr << 3))) : z8;
        #pragma unroll
        for (int cf = 0; cf < 8; ++cf) {
            int col = ch * 128 + cf * 16 + lr;
            const unsigned short* vp = Vtb + (size_t)b * 16384 + (size_t)col * 64;
            f32x4 acc = (f32x4){0.f,0.f,0.f,0.f};
            acc = __builtin_amdgcn_mfma_f32_16x16x32_bf16(a0, *(const short8*)(vp + lk), acc, 0, 0, 0);
            acc = __builtin_amdgcn_mfma_f32_16x16x32_bf16(a1, *(const short8*)(vp + 32 + lk), acc, 0, 0, 0);
            #pragma unroll
            for (int r = 0; r < 4; ++r)
                if (mr + r < 8) {
                    int row = bb * 8 + mr + r;
                    US[row * 256 + (col ^ ((row & 7) << 3))] = f2bf(acc[r]);
                }
        }
    }
    __syncthreads();

    // ---- phase 6: GRU -> HL (overwrites union; QP/AF/AT dead); pf-LN -> SA
    {
        f32x4 aR[2][2], aZ[2][2], aN[2][2], aH[2][2];
        #pragma unroll
        for (int cf = 0; cf < 2; ++cf)
            #pragma unroll
            for (int m = 0; m < 2; ++m) {
                aR[cf][m] = (f32x4){0.f,0.f,0.f,0.f}; aZ[cf][m] = (f32x4){0.f,0.f,0.f,0.f};
                aN[cf][m] = (f32x4){0.f,0.f,0.f,0.f}; aH[cf][m] = (f32x4){0.f,0.f,0.f,0.f};
            }
        #pragma unroll
        for (int g = 0; g < 3; ++g) {
            #pragma unroll
            for (int cf = 0; cf < 2; ++cf) {
                int col = wc + cf * 16 + lr;
                const unsigned short* px = gihb + (size_t)(g * 256 + col) * 256 + lk;
                const unsigned short* ph = ghhb + (size_t)(g * 256 + col) * 256 + lk;
                short8 wx[8], wh[8];
                #pragma unroll
                for (int kk = 0; kk < 8; ++kk) {
                    wx[kk] = *(const short8*)(px + kk * 32);
                    wh[kk] = *(const short8*)(ph + kk * 32);
                }
                #pragma unroll
                for (int m = 0; m < 2; ++m) {
                    #pragma unroll
                    for (int kk = 0; kk < 8; ++kk) {
                        short8 u = afrag256(US, m * 16 + lr, kk * 32 + lk);
                        short8 s = afrag256(SS, m * 16 + lr, kk * 32 + lk);
                        if (g == 0) {
                            aR[cf][m] = __builtin_amdgcn_mfma_f32_16x16x32_bf16(u, wx[kk], aR[cf][m], 0, 0, 0);
                            aR[cf][m] = __builtin_amdgcn_mfma_f32_16x16x32_bf16(s, wh[kk], aR[cf][m], 0, 0, 0);
                        } else if (g == 1) {
                            aZ[cf][m] = __builtin_amdgcn_mfma_f32_16x16x32_bf16(u, wx[kk], aZ[cf][m], 0, 0, 0);
                            aZ[cf][m] = __builtin_amdgcn_mfma_f32_16x16x32_bf16(s, wh[kk], aZ[cf][m], 0, 0, 0);
                        } else {
                            aN[cf][m] = __builtin_amdgcn_mfma_f32_16x16x32_bf16(u, wx[kk], aN[cf][m], 0, 0, 0);
                            aH[cf][m] = __builtin_amdgcn_mfma_f32_16x16x32_bf16(s, wh[kk], aH[cf][m], 0, 0, 0);
                        }
                    }
                }
            }
        }
        #pragma unroll
        for (int cf = 0; cf < 2; ++cf) {
            int col = wc + cf * 16 + lr;
            float bR  = bih[col] + bhh[col];
            float bZ  = bih[col + 256] + bhh[col + 256];
            float bXN = bih[col + 512], bHN = bhh[col + 512];
            #pragma unroll
            for (int m = 0; m < 2; ++m)
                #pragma unroll
                for (int r = 0; r < 4; ++r) {
                    int row = m * 16 + mr + r;
                    float prev = ping[((size_t)m0 + row) * 256 + col];
                    float rr = sigmoidf_(aR[cf][m][r] + bR);
                    float zz = sigmoidf_(aZ[cf][m][r] + bZ);
                    float nn = tanhf(aN[cf][m][r] + bXN + rr * (aH[cf][m][r] + bHN));
                    HL[row][col] = (1.f - zz) * nn + zz * prev;
                }
        }
    }
    __syncthreads();
    // pf-LN: HL -> SA
    {
        const float4 w4 = *(const float4*)(pfw + lane * 4);
        const float4 b4 = *(const float4*)(pfb + lane * 4);
        #pragma unroll
        for (int rr = 0; rr < 4; ++rr) {
            int row = wave * 4 + rr;
            float4 v = *(const float4*)&HL[row][lane * 4];
            float s1 = v.x + v.y + v.z + v.w;
            float s2 = v.x * v.x + v.y * v.y + v.z * v.z + v.w * v.w;
            #pragma unroll
            for (int m = 32; m >= 1; m >>= 1) { s1 += __shfl_xor(s1, m); s2 += __shfl_xor(s2, m); }
            float mu_ = s1 * (1.f / 256.f);
            float rs_ = rsqrtf(s2 * (1.f / 256.f) - mu_ * mu_ + 1e-5f);
            *(ull*)(SA + row * 256 + ((lane * 4) ^ ((row & 7) << 3))) = pack4(
                (v.x - mu_) * rs_ * w4.x + b4.x, (v.y - mu_) * rs_ * w4.y + b4.y,
                (v.z - mu_) * rs_ * w4.z + b4.z, (v.w - mu_) * rs_ * w4.w + b4.w);
        }
    }
    __syncthreads();

    // ---- phase 7: m1(relu) = SA @ m1t -> US ----
    {
        short8 w0[8], w1[8];
        const unsigned short* wp0 = m1t + (size_t)(wc + lr) * 256 + lk;
        const unsigned short* wp1 = m1t + (size_t)(wc + 16 + lr) * 256 + lk;
        #pragma unroll
        for (int kk = 0; kk < 8; ++kk) {
            w0[kk] = *(const short8*)(wp0 + kk * 32);
            w1[kk] = *(const short8*)(wp1 + kk * 32);
        }
        const float b0f = m1b[wc + lr], b1f = m1b[wc + 16 + lr];
        #pragma unroll
        for (int mt = 0; mt < 2; ++mt) {
            short8 a[8];
            #pragma unroll
            for (int kk = 0; kk < 8; ++kk) a[kk] = afrag256(SA, mt * 16 + lr, kk * 32 + lk);
            f32x4 a0 = (f32x4){0.f,0.f,0.f,0.f}, a1 = (f32x4){0.f,0.f,0.f,0.f};
            #pragma unroll
            for (int kk = 0; kk < 8; ++kk) {
                a0 = __builtin_amdgcn_mfma_f32_16x16x32_bf16(a[kk], w0[kk], a0, 0, 0, 0);
                a1 = __builtin_amdgcn_mfma_f32_16x16x32_bf16(a[kk], w1[kk], a1, 0, 0, 0);
            }
            #pragma unroll
            for (int r = 0; r < 4; ++r) {
                int row = mt * 16 + mr + r;
                US[row * 256 + ((wc + lr)      ^ ((row & 7) << 3))] = f2bf(fmaxf(a0[r] + b0f, 0.f));
                US[row * 256 + ((wc + 16 + lr) ^ ((row & 7) << 3))] = f2bf(fmaxf(a1[r] + b1f, 0.f));
            }
        }
    }
    __syncthreads();

    // ---- phase 8: m2 + residual -> HL ----
    {
        short8 w0[8], w1[8];
        const unsigned short* wp0 = m2t + (size_t)(wc + lr) * 256 + lk;
        const unsigned short* wp1 = m2t + (size_t)(wc + 16 + lr) * 256 + lk;
        #pragma unroll
        for (int kk = 0; kk < 8; ++kk) {
            w0[kk] = *(const short8*)(wp0 + kk * 32);
            w1[kk] = *(const short8*)(wp1 + kk * 32);
        }
        const float b0f = m2b[wc + lr], b1f = m2b[wc + 16 + lr];
        #pragma unroll
        for (int mt = 0; mt < 2; ++mt) {
            short8 a[8];
            #pragma unroll
            for (int kk = 0; kk < 8; ++kk) a[kk] = afrag256(US, mt * 16 + lr, kk * 32 + lk);
            f32x4 a0 = (f32x4){0.f,0.f,0.f,0.f}, a1 = (f32x4){0.f,0.f,0.f,0.f};
            #pragma unroll
            for (int kk = 0; kk < 8; ++kk) {
                a0 = __builtin_amdgcn_mfma_f32_16x16x32_bf16(a[kk], w0[kk], a0, 0, 0, 0);
                a1 = __builtin_amdgcn_mfma_f32_16x16x32_bf16(a[kk], w1[kk], a1, 0, 0, 0);
            }
            #pragma unroll
            for (int r = 0; r < 4; ++r) {
                int row = mt * 16 + mr + r;
                HL[row][wc + lr]      = a0[r] + b0f + HL[row][wc + lr];
                HL[row][wc + 16 + lr] = a1[r] + b1f + HL[row][wc + 16 + lr];
            }
        }
    }
    __syncthreads();

    // ---- epilogue ----
    if (last) {
        #pragma unroll
        for (int rr = 0; rr < 4; ++rr) {
            int row = wave * 4 + rr;
            *(float4*)(outf + ((size_t)m0 + row) * 256 + lane * 4) =
                *(const float4*)&HL[row][lane * 4];
        }
    } else {
        const float4 w4 = *(const float4*)(nsw + lane * 4);
        const float4 b4 = *(const float4*)(nsb + lane * 4);
        #pragma unroll
        for (int rr = 0; rr < 4; ++rr) {
            int row = wave * 4 + rr;
            float4 v = *(const float4*)&HL[row][lane * 4];
            float s1 = v.x + v.y + v.z + v.w;
            float s2 = v.x * v.x + v.y * v.y + v.z * v.z + v.w * v.w;
            #pragma unroll
            for (int m = 32; m >= 1; m >>= 1) { s1 += __shfl_xor(s1, m); s2 += __shfl_xor(s2, m); }
            float mu_ = s1 * (1.f / 256.f);
            float rs_ = rsqrtf(s2 * (1.f / 256.f) - mu_ * mu_ + 1e-5f);
            size_t off = ((size_t)m0 + row) * 256 + lane * 4;
            *(float4*)(ping + off) = v;
            *(ull*)(sraw + off) = pack4(v.x, v.y, v.z, v.w);
            *(ull*)(lnq + off) = pack4(
                (v.x - mu_) * rs_ * w4.x + b4.x, (v.y - mu_) * rs_ * w4.y + b4.y,
                (v.z - mu_) * rs_ * w4.z + b4.z, (v.w - mu_) * rs_ * w4.w + b4.w);
        }
    }
}

// ------------------------------------------------------------------
extern "C" void kernel_launch(void* const* d_in, const int* in_sizes, int n_in,
                              void* d_out, int out_size, void* d_ws, size_t ws_size,
                              hipStream_t stream) {
    (void)in_sizes; (void)n_in; (void)ws_size; (void)out_size;
    unsigned short* wsb  = (unsigned short*)d_ws;
    unsigned short* ksb  = wsb + (1u << 20);         // K
    unsigned short* vtb  = ksb + 16777216;           // V^T
    float* ping = (float*)(vtb + 16777216);
    unsigned short* srawb = (unsigned short*)(ping + 2097152);
    unsigned short* lnqb  = srawb + 2097152;

    const unsigned short* f1t  = wsb;
    const unsigned short* f2t  = wsb + 65536;
    const unsigned short* kt   = wsb + 131072;
    const unsigned short* vwt  = wsb + 196608;
    const unsigned short* qt   = wsb + 262144;
    const unsigned short* m1t  = wsb + 327680;
    const unsigned short* m2t  = wsb + 393216;
    const unsigned short* gihb = wsb + 458752;
    const unsigned short* ghhb = wsb + 655360;

    convert_weights<<<dim3(1664), dim3(512), 0, stream>>>(
        (const float*)d_in[6],  (const float*)d_in[8],  (const float*)d_in[14],
        (const float*)d_in[16], (const float*)d_in[12], (const float*)d_in[26],
        (const float*)d_in[28], (const float*)d_in[18], (const float*)d_in[19], wsb);

    enc_kernel<<<dim3(1024), dim3(512), 0, stream>>>(
        (const float*)d_in[0], (const float*)d_in[2], (const float*)d_in[3],
        (const float*)d_in[4], (const float*)d_in[5],
        f1t, (const float*)d_in[7],
        f2t, (const float*)d_in[9],
        (const float*)d_in[10], (const float*)d_in[11],
        kt, (const float*)d_in[15], vwt, (const float*)d_in[17],
        ksb, vtb);

    slot_init<<<dim3(1024), dim3(512), 0, stream>>>(
        (const float*)d_in[30], (const float*)d_in[31], (const float*)d_in[1],
        (const float*)d_in[22], (const float*)d_in[23], ping, srawb, lnqb);

    for (int it = 0; it < 5; ++it) {
        iter_kernel<<<dim3(256), dim3(512), 0, stream>>>(
            ksb, vtb, qt, gihb, ghhb, m1t, m2t,
            (const float*)d_in[13], (const float*)d_in[20], (const float*)d_in[21],
            (const float*)d_in[24], (const float*)d_in[25],
            (const float*)d_in[27], (const float*)d_in[29],
            (const float*)d_in[22], (const float*)d_in[23],
            ping, srawb, lnqb,
            (float*)d_out, it == 4 ? 1 : 0);
    }
}

// Round 15
// 388.112 us; speedup vs baseline: 1.1275x; 1.0487x over previous
//
#include <hip/hip_runtime.h>
#include <math.h>

// ------------------------------------------------------------------
// R15 = R14 (best, 407us) with enc VALU-diet:
//  - pos-embed table precomputed once (bf16, [d][r] transposed) in the
//    convert kernel; enc phase A is load+add+pack.
//  - enln w/b converted to bf16 (halves enLN operand traffic).
//  - slot_init folded into convert kernel (7 dispatches total).
// iter = R14 verbatim (80KB LDS, 2 blocks/CU).
// B=1024, D=256, tok=64, slots=8, iters=5.
// ws (u16): W:0..851968 pos_t:851968 enwb:868352 enbb:884736 (end 901120)
//           ks:1<<20  vt:+16M  ping f32 / sraw / lnq after.
// ------------------------------------------------------------------

typedef __attribute__((ext_vector_type(8))) short short8;
typedef __attribute__((ext_vector_type(4))) float f32x4;
typedef unsigned long long ull;

__device__ __forceinline__ unsigned short f2bf(float f) {
    union { float f; unsigned u; } x; x.f = f;
    unsigned r = x.u + 0x7fffu + ((x.u >> 16) & 1u);
    return (unsigned short)(r >> 16);
}
__device__ __forceinline__ float bf2f(unsigned short h) {
    union { unsigned u; float f; } x; x.u = ((unsigned)h) << 16;
    return x.f;
}
__device__ __forceinline__ float sigmoidf_(float x) { return 1.f / (1.f + expf(-x)); }
__device__ __forceinline__ ull pack4(float a, float b, float c, float d) {
    return (ull)f2bf(a) | ((ull)f2bf(b) << 16) | ((ull)f2bf(c) << 32) | ((ull)f2bf(d) << 48);
}
__device__ __forceinline__ short8 afrag256(const unsigned short* buf, int row, int k) {
    return *(const short8*)(buf + row * 256 + (k ^ ((row & 7) << 3)));
}

// ---------------- convert weights + pos table + enln bf16 + slot init -----
__launch_bounds__(512)
__global__ void prep_kernel(
    const float* __restrict__ f1W, const float* __restrict__ f2W,
    const float* __restrict__ kW,  const float* __restrict__ vW,
    const float* __restrict__ qW,  const float* __restrict__ m1W,
    const float* __restrict__ m2W, const float* __restrict__ gih,
    const float* __restrict__ ghh,
    const float* __restrict__ posW, const float* __restrict__ posb,
    const float* __restrict__ enw,  const float* __restrict__ enb,
    const float* __restrict__ smu,  const float* __restrict__ ssig,
    const float* __restrict__ noise,
    const float* __restrict__ nsw,  const float* __restrict__ nsb,
    unsigned short* __restrict__ out,
    float* __restrict__ ping, unsigned short* __restrict__ sraw,
    unsigned short* __restrict__ lnq)
{
    if (blockIdx.x < 1760) {
        int id = blockIdx.x * 512 + threadIdx.x;
        if (id < 458752) {                      // transpose [k][n] -> [n][k]
            int mi = id >> 16, e = id & 65535;
            int k = e >> 8, n = e & 255;
            const float* src = mi == 0 ? f1W : mi == 1 ? f2W : mi == 2 ? kW :
                               mi == 3 ? vW  : mi == 4 ? qW  : mi == 5 ? m1W : m2W;
            out[mi * 65536 + n * 256 + k] = f2bf(src[e]);
        } else if (id < 851968) {               // gih/ghh already [n][k]
            int e = id - 458752;
            const float* src = e < 196608 ? gih : ghh;
            int ee = e < 196608 ? e : e - 196608;
            out[458752 + e] = f2bf(src[ee]);
        } else if (id < 868352) {               // pos table, transposed [d][r]
            int e = id - 851968;
            int d = e >> 6, r = e & 63;
            float fh = (float)(r >> 3) * (1.f / 7.f);
            float fw = (float)(r & 7) * (1.f / 7.f);
            out[id] = f2bf(fh * posW[d] + fw * posW[256 + d] +
                           (1.f - fh) * posW[512 + d] + (1.f - fw) * posW[768 + d] + posb[d]);
        } else if (id < 884736) {               // enln_w bf16
            out[id] = f2bf(enw[id - 868352]);
        } else if (id < 901120) {               // enln_b bf16
            out[id] = f2bf(enb[id - 884736]);
        }
    } else {
        // slot init (verified body)
        const int t = threadIdx.x, lane = t & 63, wave = t >> 6;
        const int row = (blockIdx.x - 1760) * 8 + wave;
        const int c = lane * 4;
        float4 n4 = *(const float4*)(noise + (size_t)row * 256 + c);
        float4 m4 = *(const float4*)(smu + c);
        float4 g4 = *(const float4*)(ssig + c);
        float v0 = m4.x + expf(0.5f * g4.x) * n4.x;
        float v1 = m4.y + expf(0.5f * g4.y) * n4.y;
        float v2 = m4.z + expf(0.5f * g4.z) * n4.z;
        float v3 = m4.w + expf(0.5f * g4.w) * n4.w;
        float s1 = v0 + v1 + v2 + v3;
        float s2 = v0 * v0 + v1 * v1 + v2 * v2 + v3 * v3;
        #pragma unroll
        for (int m = 32; m >= 1; m >>= 1) { s1 += __shfl_xor(s1, m); s2 += __shfl_xor(s2, m); }
        float mu_ = s1 * (1.f / 256.f);
        float rs_ = rsqrtf(s2 * (1.f / 256.f) - mu_ * mu_ + 1e-5f);
        float4 w4 = *(const float4*)(nsw + c);
        float4 b4 = *(const float4*)(nsb + c);
        *(float4*)(ping + (size_t)row * 256 + c) = make_float4(v0, v1, v2, v3);
        *(ull*)(sraw + (size_t)row * 256 + c) = pack4(v0, v1, v2, v3);
        *(ull*)(lnq + (size_t)row * 256 + c) = pack4(
            (v0 - mu_) * rs_ * w4.x + b4.x, (v1 - mu_) * rs_ * w4.y + b4.y,
            (v2 - mu_) * rs_ * w4.z + b4.z, (v3 - mu_) * rs_ * w4.w + b4.w);
    }
}

// ---------------- enc: pos(table) + enLN(bf16) + f1 + f2 + niLN + K + V ---
__launch_bounds__(512)
__global__ void enc_kernel(const float* __restrict__ g_in,
                           const unsigned short* __restrict__ pos_t,
                           const unsigned short* __restrict__ enwb,
                           const unsigned short* __restrict__ enbb,
                           const unsigned short* __restrict__ f1t, const float* __restrict__ f1b,
                           const unsigned short* __restrict__ f2t, const float* __restrict__ f2b,
                           const float* __restrict__ niw, const float* __restrict__ nib,
                           const unsigned short* __restrict__ kt,  const float* __restrict__ kb,
                           const unsigned short* __restrict__ vwt, const float* __restrict__ vb,
                           unsigned short* __restrict__ ks, unsigned short* __restrict__ vt)
{
    __shared__ unsigned short xs[64 * 256];
    __shared__ float red[16];
    const int b = blockIdx.x, t = threadIdx.x, lane = t & 63, wave = t >> 6;
    const int lr = lane & 15, lk = (lane >> 4) * 8, mr = (lane >> 4) * 4;
    const int wc = wave * 32;

    // ---- phase A: load + pos table add + stats ----
    const float* inb = g_in + (size_t)b * 16384;
    float psum = 0.f, psq = 0.f;
    for (int i = 0; i < 8; ++i) {
        int idx4 = i * 512 + t;
        int d = idx4 >> 4;
        int r0 = (idx4 & 15) << 2;
        float4 v = ((const float4*)inb)[idx4];
        ull pp = *(const ull*)(pos_t + d * 64 + r0);
        float vals[4] = {v.x, v.y, v.z, v.w};
        #pragma unroll
        for (int q = 0; q < 4; ++q) {
            int r = r0 + q;
            float x = vals[q] + bf2f((unsigned short)(pp >> (16 * q)));
            xs[r * 256 + (d ^ ((r & 7) << 3))] = f2bf(x);
            psum += x; psq += x * x;
        }
    }
    #pragma unroll
    for (int m = 32; m >= 1; m >>= 1) { psum += __shfl_xor(psum, m); psq += __shfl_xor(psq, m); }
    if (lane == 0) { red[wave] = psum; red[8 + wave] = psq; }
    __syncthreads();
    // ---- global enLN in LDS (bf16 w/b) ----
    {
        float tsum = 0.f, tsq = 0.f;
        #pragma unroll
        for (int w2 = 0; w2 < 8; ++w2) { tsum += red[w2]; tsq += red[8 + w2]; }
        float mu = tsum * (1.f / 16384.f);
        float rs = rsqrtf(tsq * (1.f / 16384.f) - mu * mu + 1e-5f);
        int row = t >> 3, c0 = (t & 7) * 32;
        for (int j = 0; j < 8; ++j) {
            int c = c0 + j * 4;
            ull* p = (ull*)(xs + row * 256 + (c ^ ((row & 7) << 3)));
            ull pk = *p;
            ull wp = *(const ull*)(enwb + row * 256 + c);
            ull bp = *(const ull*)(enbb + row * 256 + c);
            float v0 = (bf2f((unsigned short)pk)         - mu) * rs * bf2f((unsigned short)wp)         + bf2f((unsigned short)bp);
            float v1 = (bf2f((unsigned short)(pk >> 16)) - mu) * rs * bf2f((unsigned short)(wp >> 16)) + bf2f((unsigned short)(bp >> 16));
            float v2 = (bf2f((unsigned short)(pk >> 32)) - mu) * rs * bf2f((unsigned short)(wp >> 32)) + bf2f((unsigned short)(bp >> 32));
            float v3 = (bf2f((unsigned short)(pk >> 48)) - mu) * rs * bf2f((unsigned short)(wp >> 48)) + bf2f((unsigned short)(bp >> 48));
            *p = pack4(v0, v1, v2, v3);
        }
    }
    __syncthreads();

    // ---- f1(relu) reg-staged back into xs (verified) ----
    {
        f32x4 acc[4][2];
        short8 w0[8], w1[8];
        const unsigned short* wp0 = f1t + (size_t)(wc + lr) * 256 + lk;
        const unsigned short* wp1 = f1t + (size_t)(wc + 16 + lr) * 256 + lk;
        #pragma unroll
        for (int kk = 0; kk < 8; ++kk) {
            w0[kk] = *(const short8*)(wp0 + kk * 32);
            w1[kk] = *(const short8*)(wp1 + kk * 32);
        }
        #pragma unroll
        for (int mt = 0; mt < 4; ++mt) {
            acc[mt][0] = (f32x4){0.f,0.f,0.f,0.f};
            acc[mt][1] = (f32x4){0.f,0.f,0.f,0.f};
            short8 a[8];
            #pragma unroll
            for (int kk = 0; kk < 8; ++kk) a[kk] = afrag256(xs, mt * 16 + lr, kk * 32 + lk);
            #pragma unroll
            for (int kk = 0; kk < 8; ++kk) {
                acc[mt][0] = __builtin_amdgcn_mfma_f32_16x16x32_bf16(a[kk], w0[kk], acc[mt][0], 0, 0, 0);
                acc[mt][1] = __builtin_amdgcn_mfma_f32_16x16x32_bf16(a[kk], w1[kk], acc[mt][1], 0, 0, 0);
            }
        }
        __syncthreads();
        const float b0 = f1b[wc + lr], b1 = f1b[wc + 16 + lr];
        #pragma unroll
        for (int mt = 0; mt < 4; ++mt)
            #pragma unroll
            for (int r = 0; r < 4; ++r) {
                int lrow = mt * 16 + mr + r;
                xs[lrow * 256 + ((wc + lr)      ^ ((lrow & 7) << 3))] = f2bf(fmaxf(acc[mt][0][r] + b0, 0.f));
                xs[lrow * 256 + ((wc + 16 + lr) ^ ((lrow & 7) << 3))] = f2bf(fmaxf(acc[mt][1][r] + b1, 0.f));
            }
    }
    __syncthreads();

    // ---- f2(relu) reg-staged back into xs (verified) ----
    {
        f32x4 acc[4][2];
        short8 w0[8], w1[8];
        const unsigned short* wp0 = f2t + (size_t)(wc + lr) * 256 + lk;
        const unsigned short* wp1 = f2t + (size_t)(wc + 16 + lr) * 256 + lk;
        #pragma unroll
        for (int kk = 0; kk < 8; ++kk) {
            w0[kk] = *(const short8*)(wp0 + kk * 32);
            w1[kk] = *(const short8*)(wp1 + kk * 32);
        }
        #pragma unroll
        for (int mt = 0; mt < 4; ++mt) {
            acc[mt][0] = (f32x4){0.f,0.f,0.f,0.f};
            acc[mt][1] = (f32x4){0.f,0.f,0.f,0.f};
            short8 a[8];
            #pragma unroll
            for (int kk = 0; kk < 8; ++kk) a[kk] = afrag256(xs, mt * 16 + lr, kk * 32 + lk);
            #pragma unroll
            for (int kk = 0; kk < 8; ++kk) {
                acc[mt][0] = __builtin_amdgcn_mfma_f32_16x16x32_bf16(a[kk], w0[kk], acc[mt][0], 0, 0, 0);
                acc[mt][1] = __builtin_amdgcn_mfma_f32_16x16x32_bf16(a[kk], w1[kk], acc[mt][1], 0, 0, 0);
            }
        }
        __syncthreads();
        const float b0 = f2b[wc + lr], b1 = f2b[wc + 16 + lr];
        #pragma unroll
        for (int mt = 0; mt < 4; ++mt)
            #pragma unroll
            for (int r = 0; r < 4; ++r) {
                int lrow = mt * 16 + mr + r;
                xs[lrow * 256 + ((wc + lr)      ^ ((lrow & 7) << 3))] = f2bf(fmaxf(acc[mt][0][r] + b0, 0.f));
                xs[lrow * 256 + ((wc + 16 + lr) ^ ((lrow & 7) << 3))] = f2bf(fmaxf(acc[mt][1][r] + b1, 0.f));
            }
    }
    __syncthreads();

    // ---- niLN in place (verified) ----
    {
        const float4 w4 = *(const float4*)(niw + lane * 4);
        const float4 b4 = *(const float4*)(nib + lane * 4);
        for (int rr = 0; rr < 8; ++rr) {
            int row = wave * 8 + rr;
            ull* p = (ull*)(xs + row * 256 + ((lane * 4) ^ ((row & 7) << 3)));
            ull pk = *p;
            float v0 = bf2f((unsigned short)pk),         v1 = bf2f((unsigned short)(pk >> 16));
            float v2 = bf2f((unsigned short)(pk >> 32)), v3 = bf2f((unsigned short)(pk >> 48));
            float s1 = v0 + v1 + v2 + v3;
            float s2 = v0 * v0 + v1 * v1 + v2 * v2 + v3 * v3;
            #pragma unroll
            for (int m = 32; m >= 1; m >>= 1) { s1 += __shfl_xor(s1, m); s2 += __shfl_xor(s2, m); }
            float mu_ = s1 * (1.f / 256.f);
            float rs_ = rsqrtf(s2 * (1.f / 256.f) - mu_ * mu_ + 1e-5f);
            *p = pack4((v0 - mu_) * rs_ * w4.x + b4.x, (v1 - mu_) * rs_ * w4.y + b4.y,
                       (v2 - mu_) * rs_ * w4.z + b4.z, (v3 - mu_) * rs_ * w4.w + b4.w);
        }
    }
    __syncthreads();

    // ---- K GEMM -> ks (verified) ----
    {
        short8 w0[8], w1[8];
        const unsigned short* wp0 = kt + (size_t)(wc + lr) * 256 + lk;
        const unsigned short* wp1 = kt + (size_t)(wc + 16 + lr) * 256 + lk;
        #pragma unroll
        for (int kk = 0; kk < 8; ++kk) {
            w0[kk] = *(const short8*)(wp0 + kk * 32);
            w1[kk] = *(const short8*)(wp1 + kk * 32);
        }
        const float b0 = kb[wc + lr], b1 = kb[wc + 16 + lr];
        for (int mt = 0; mt < 4; ++mt) {
            short8 a[8];
            #pragma unroll
            for (int kk = 0; kk < 8; ++kk) a[kk] = afrag256(xs, mt * 16 + lr, kk * 32 + lk);
            f32x4 a0 = (f32x4){0.f,0.f,0.f,0.f}, a1 = (f32x4){0.f,0.f,0.f,0.f};
            #pragma unroll
            for (int kk = 0; kk < 8; ++kk) {
                a0 = __builtin_amdgcn_mfma_f32_16x16x32_bf16(a[kk], w0[kk], a0, 0, 0, 0);
                a1 = __builtin_amdgcn_mfma_f32_16x16x32_bf16(a[kk], w1[kk], a1, 0, 0, 0);
            }
            #pragma unroll
            for (int r = 0; r < 4; ++r) {
                size_t row = (size_t)b * 64 + mt * 16 + mr + r;
                ks[row * 256 + wc + lr]      = f2bf(a0[r] + b0);
                ks[row * 256 + wc + 16 + lr] = f2bf(a1[r] + b1);
            }
        }
    }
    // ---- V GEMM -> vt (verified) ----
    {
        short8 w0[8], w1[8];
        const unsigned short* wp0 = vwt + (size_t)(wc + lr) * 256 + lk;
        const unsigned short* wp1 = vwt + (size_t)(wc + 16 + lr) * 256 + lk;
        #pragma unroll
        for (int kk = 0; kk < 8; ++kk) {
            w0[kk] = *(const short8*)(wp0 + kk * 32);
            w1[kk] = *(const short8*)(wp1 + kk * 32);
        }
        const float b0 = vb[wc + lr], b1 = vb[wc + 16 + lr];
        for (int mt = 0; mt < 4; ++mt) {
            short8 a[8];
            #pragma unroll
            for (int kk = 0; kk < 8; ++kk) a[kk] = afrag256(xs, mt * 16 + lr, kk * 32 + lk);
            f32x4 a0 = (f32x4){0.f,0.f,0.f,0.f}, a1 = (f32x4){0.f,0.f,0.f,0.f};
            #pragma unroll
            for (int kk = 0; kk < 8; ++kk) {
                a0 = __builtin_amdgcn_mfma_f32_16x16x32_bf16(a[kk], w0[kk], a0, 0, 0, 0);
                a1 = __builtin_amdgcn_mfma_f32_16x16x32_bf16(a[kk], w1[kk], a1, 0, 0, 0);
            }
            int t0 = mt * 16 + mr;
            *(ull*)(vt + (size_t)b * 16384 + (size_t)(wc + lr) * 64 + t0) =
                pack4(a0[0] + b0, a0[1] + b0, a0[2] + b0, a0[3] + b0);
            *(ull*)(vt + (size_t)b * 16384 + (size_t)(wc + 16 + lr) * 64 + t0) =
                pack4(a1[0] + b1, a1[1] + b1, a1[2] + b1, a1[3] + b1);
        }
    }
}

// ---------------- iter: R14 verbatim (80KB LDS, 2 blocks/CU) -------------
__launch_bounds__(512)
__global__ void iter_kernel(
    const unsigned short* __restrict__ Kb, const unsigned short* __restrict__ Vtb,
    const unsigned short* __restrict__ qt,
    const unsigned short* __restrict__ gihb, const unsigned short* __restrict__ ghhb,
    const unsigned short* __restrict__ m1t,  const unsigned short* __restrict__ m2t,
    const float* __restrict__ qb,  const float* __restrict__ bih, const float* __restrict__ bhh,
    const float* __restrict__ pfw, const float* __restrict__ pfb,
    const float* __restrict__ m1b, const float* __restrict__ m2b,
    const float* __restrict__ nsw, const float* __restrict__ nsb,
    float* __restrict__ ping, unsigned short* __restrict__ sraw,
    unsigned short* __restrict__ lnq,
    float* __restrict__ outf, int last)
{
    __shared__ unsigned short SA[32 * 256];
    __shared__ unsigned short SS[32 * 256];
    __shared__ unsigned short US[32 * 256];
    __shared__ __align__(16) unsigned char UN[32768];
    unsigned short* QP = (unsigned short*)UN;
    float*          AFb = (float*)(UN + 16384);
    unsigned short* ATb = (unsigned short*)(UN + 16384 + 9216);
    float (*HL)[256] = (float(*)[256])UN;

    const int t = threadIdx.x, lane = t & 63, wave = t >> 6;
    const int m0 = blockIdx.x * 32;
    const int b0 = blockIdx.x * 4;
    const int lr = lane & 15, lk = (lane >> 4) * 8, mr = (lane >> 4) * 4;
    const int wc = wave * 32;
    const short8 z8 = (short8){0,0,0,0,0,0,0,0};

    for (int i = 0; i < 4; ++i) {
        int id = t + 512 * i;
        int row = id >> 6, c4 = (id & 63) * 4;
        size_t g = ((size_t)m0 + row) * 256 + c4;
        int sw = c4 ^ ((row & 7) << 3);
        *(ull*)(SA + row * 256 + sw) = *(const ull*)(lnq + g);
        *(ull*)(SS + row * 256 + sw) = *(const ull*)(sraw + g);
    }
    __syncthreads();

    // phase 1: q
    {
        short8 w0[8], w1[8];
        const unsigned short* wp0 = qt + (size_t)(wc + lr) * 256 + lk;
        const unsigned short* wp1 = qt + (size_t)(wc + 16 + lr) * 256 + lk;
        #pragma unroll
        for (int kk = 0; kk < 8; ++kk) {
            w0[kk] = *(const short8*)(wp0 + kk * 32);
            w1[kk] = *(const short8*)(wp1 + kk * 32);
        }
        const float bq0 = qb[wc + lr], bq1 = qb[wc + 16 + lr];
        #pragma unroll
        for (int mt = 0; mt < 2; ++mt) {
            short8 a[8];
            #pragma unroll
            for (int kk = 0; kk < 8; ++kk) a[kk] = afrag256(SA, mt * 16 + lr, kk * 32 + lk);
            f32x4 a0 = (f32x4){0.f,0.f,0.f,0.f}, a1 = (f32x4){0.f,0.f,0.f,0.f};
            #pragma unroll
            for (int kk = 0; kk < 8; ++kk) {
                a0 = __builtin_amdgcn_mfma_f32_16x16x32_bf16(a[kk], w0[kk], a0, 0, 0, 0);
                a1 = __builtin_amdgcn_mfma_f32_16x16x32_bf16(a[kk], w1[kk], a1, 0, 0, 0);
            }
            #pragma unroll
            for (int r = 0; r < 4; ++r) {
                int row = mt * 16 + mr + r;
                int bb = row >> 3, sr = row & 7;
                unsigned short* q = QP + bb * 2048;
                q[sr * 256 + ((wc + lr)      ^ (sr << 3))] = f2bf(a0[r] + bq0);
                q[sr * 256 + ((wc + 16 + lr) ^ (sr << 3))] = f2bf(a1[r] + bq1);
            }
        }
    }
    __syncthreads();

    // phase 2: dots (predicated A rows)
    {
        const int bb = wave >> 1, th = wave & 1;
        const int b = b0 + bb;
        const unsigned short* q = QP + bb * 2048;
        short8 af[8];
        #pragma unroll
        for (int kk = 0; kk < 8; ++kk)
            af[kk] = (lr < 8) ? *(const short8*)(q + lr * 256 + ((kk * 32 + lk) ^ (lr << 3))) : z8;
        #pragma unroll
        for (int tf = 0; tf < 2; ++tf) {
            int n0 = th * 32 + tf * 16;
            f32x4 acc = (f32x4){0.f,0.f,0.f,0.f};
            const unsigned short* kp = Kb + ((size_t)b * 64 + n0 + lr) * 256 + lk;
            #pragma unroll
            for (int kk = 0; kk < 8; ++kk)
                acc = __builtin_amdgcn_mfma_f32_16x16x32_bf16(af[kk], *(const short8*)(kp + kk * 32), acc, 0, 0, 0);
            #pragma unroll
            for (int r = 0; r < 4; ++r)
                if (mr + r < 8) AFb[bb * 576 + (mr + r) * 72 + n0 + lr] = acc[r] * 0.0625f;
        }
    }
    __syncthreads();

    // phase 3: softmax over slots + eps
    if (t < 256) {
        int b2 = t >> 6, tok = t & 63;
        float* A = AFb + b2 * 576;
        float mx = A[tok];
        #pragma unroll
        for (int s = 1; s < 8; ++s) mx = fmaxf(mx, A[s * 72 + tok]);
        float e[8], den = 0.f;
        #pragma unroll
        for (int s = 0; s < 8; ++s) { e[s] = expf(A[s * 72 + tok] - mx); den += e[s]; }
        float inv = 1.f / den;
        #pragma unroll
        for (int s = 0; s < 8; ++s) A[s * 72 + tok] = e[s] * inv + 1e-8f;
    }
    __syncthreads();

    // phase 4: renormalize over tokens -> AT
    #pragma unroll
    for (int j = 0; j < 4; ++j) {
        int row = wave * 4 + j;
        int bb = row >> 3, sr = row & 7;
        float v = AFb[bb * 576 + sr * 72 + lane];
        float ssum = v;
        #pragma unroll
        for (int m = 32; m >= 1; m >>= 1) ssum += __shfl_xor(ssum, m);
        (ATb + bb * 512)[sr * 64 + (lane ^ (sr << 3))] = f2bf(v / ssum);
    }
    __syncthreads();

    // phase 5: updates = attn @ V -> US (predicated A rows)
    {
        const int bb = wave >> 1, ch = wave & 1;
        const int b = b0 + bb;
        const unsigned short* at = ATb + bb * 512;
        short8 a0 = (lr < 8) ? *(const short8*)(at + lr * 64 + ((lk)      ^ (lr << 3))) : z8;
        short8 a1 = (lr < 8) ? *(const short8*)(at + lr * 64 + ((32 + lk) ^ (lr << 3))) : z8;
        #pragma unroll
        for (int cf = 0; cf < 8; ++cf) {
            int col = ch * 128 + cf * 16 + lr;
            const unsigned short* vp = Vtb + (size_t)b * 16384 + (size_t)col * 64;
            f32x4 acc = (f32x4){0.f,0.f,0.f,0.f};
            acc = __builtin_amdgcn_mfma_f32_16x16x32_bf16(a0, *(const short8*)(vp + lk), acc, 0, 0, 0);
            acc = __builtin_amdgcn_mfma_f32_16x16x32_bf16(a1, *(const short8*)(vp + 32 + lk), acc, 0, 0, 0);
            #pragma unroll
            for (int r = 0; r < 4; ++r)
                if (mr + r < 8) {
                    int row = bb * 8 + mr + r;
                    US[row * 256 + (col ^ ((row & 7) << 3))] = f2bf(acc[r]);
                }
        }
    }
    __syncthreads();

    // phase 6: GRU -> HL; pf-LN -> SA
    {
        f32x4 aR[2][2], aZ[2][2], aN[2][2], aH[2][2];
        #pragma unroll
        for (int cf = 0; cf < 2; ++cf)
            #pragma unroll
            for (int m = 0; m < 2; ++m) {
                aR[cf][m] = (f32x4){0.f,0.f,0.f,0.f}; aZ[cf][m] = (f32x4){0.f,0.f,0.f,0.f};
                aN[cf][m] = (f32x4){0.f,0.f,0.f,0.f}; aH[cf][m] = (f32x4){0.f,0.f,0.f,0.f};
            }
        #pragma unroll
        for (int g = 0; g < 3; ++g) {
            #pragma unroll
            for (int cf = 0; cf < 2; ++cf) {
                int col = wc + cf * 16 + lr;
                const unsigned short* px = gihb + (size_t)(g * 256 + col) * 256 + lk;
                const unsigned short* ph = ghhb + (size_t)(g * 256 + col) * 256 + lk;
                short8 wx[8], wh[8];
                #pragma unroll
                for (int kk = 0; kk < 8; ++kk) {
                    wx[kk] = *(const short8*)(px + kk * 32);
                    wh[kk] = *(const short8*)(ph + kk * 32);
                }
                #pragma unroll
                for (int m = 0; m < 2; ++m) {
                    #pragma unroll
                    for (int kk = 0; kk < 8; ++kk) {
                        short8 u = afrag256(US, m * 16 + lr, kk * 32 + lk);
                        short8 s = afrag256(SS, m * 16 + lr, kk * 32 + lk);
                        if (g == 0) {
                            aR[cf][m] = __builtin_amdgcn_mfma_f32_16x16x32_bf16(u, wx[kk], aR[cf][m], 0, 0, 0);
                            aR[cf][m] = __builtin_amdgcn_mfma_f32_16x16x32_bf16(s, wh[kk], aR[cf][m], 0, 0, 0);
                        } else if (g == 1) {
                            aZ[cf][m] = __builtin_amdgcn_mfma_f32_16x16x32_bf16(u, wx[kk], aZ[cf][m], 0, 0, 0);
                            aZ[cf][m] = __builtin_amdgcn_mfma_f32_16x16x32_bf16(s, wh[kk], aZ[cf][m], 0, 0, 0);
                        } else {
                            aN[cf][m] = __builtin_amdgcn_mfma_f32_16x16x32_bf16(u, wx[kk], aN[cf][m], 0, 0, 0);
                            aH[cf][m] = __builtin_amdgcn_mfma_f32_16x16x32_bf16(s, wh[kk], aH[cf][m], 0, 0, 0);
                        }
                    }
                }
            }
        }
        #pragma unroll
        for (int cf = 0; cf < 2; ++cf) {
            int col = wc + cf * 16 + lr;
            float bR  = bih[col] + bhh[col];
            float bZ  = bih[col + 256] + bhh[col + 256];
            float bXN = bih[col + 512], bHN = bhh[col + 512];
            #pragma unroll
            for (int m = 0; m < 2; ++m)
                #pragma unroll
                for (int r = 0; r < 4; ++r) {
                    int row = m * 16 + mr + r;
                    float prev = ping[((size_t)m0 + row) * 256 + col];
                    float rr = sigmoidf_(aR[cf][m][r] + bR);
                    float zz = sigmoidf_(aZ[cf][m][r] + bZ);
                    float nn = tanhf(aN[cf][m][r] + bXN + rr * (aH[cf][m][r] + bHN));
                    HL[row][col] = (1.f - zz) * nn + zz * prev;
                }
        }
    }
    __syncthreads();
    {
        const float4 w4 = *(const float4*)(pfw + lane * 4);
        const float4 b4 = *(const float4*)(pfb + lane * 4);
        #pragma unroll
        for (int rr = 0; rr < 4; ++rr) {
            int row = wave * 4 + rr;
            float4 v = *(const float4*)&HL[row][lane * 4];
            float s1 = v.x + v.y + v.z + v.w;
            float s2 = v.x * v.x + v.y * v.y + v.z * v.z + v.w * v.w;
            #pragma unroll
            for (int m = 32; m >= 1; m >>= 1) { s1 += __shfl_xor(s1, m); s2 += __shfl_xor(s2, m); }
            float mu_ = s1 * (1.f / 256.f);
            float rs_ = rsqrtf(s2 * (1.f / 256.f) - mu_ * mu_ + 1e-5f);
            *(ull*)(SA + row * 256 + ((lane * 4) ^ ((row & 7) << 3))) = pack4(
                (v.x - mu_) * rs_ * w4.x + b4.x, (v.y - mu_) * rs_ * w4.y + b4.y,
                (v.z - mu_) * rs_ * w4.z + b4.z, (v.w - mu_) * rs_ * w4.w + b4.w);
        }
    }
    __syncthreads();

    // phase 7: m1(relu)
    {
        short8 w0[8], w1[8];
        const unsigned short* wp0 = m1t + (size_t)(wc + lr) * 256 + lk;
        const unsigned short* wp1 = m1t + (size_t)(wc + 16 + lr) * 256 + lk;
        #pragma unroll
        for (int kk = 0; kk < 8; ++kk) {
            w0[kk] = *(const short8*)(wp0 + kk * 32);
            w1[kk] = *(const short8*)(wp1 + kk * 32);
        }
        const float b0f = m1b[wc + lr], b1f = m1b[wc + 16 + lr];
        #pragma unroll
        for (int mt = 0; mt < 2; ++mt) {
            short8 a[8];
            #pragma unroll
            for (int kk = 0; kk < 8; ++kk) a[kk] = afrag256(SA, mt * 16 + lr, kk * 32 + lk);
            f32x4 a0 = (f32x4){0.f,0.f,0.f,0.f}, a1 = (f32x4){0.f,0.f,0.f,0.f};
            #pragma unroll
            for (int kk = 0; kk < 8; ++kk) {
                a0 = __builtin_amdgcn_mfma_f32_16x16x32_bf16(a[kk], w0[kk], a0, 0, 0, 0);
                a1 = __builtin_amdgcn_mfma_f32_16x16x32_bf16(a[kk], w1[kk], a1, 0, 0, 0);
            }
            #pragma unroll
            for (int r = 0; r < 4; ++r) {
                int row = mt * 16 + mr + r;
                US[row * 256 + ((wc + lr)      ^ ((row & 7) << 3))] = f2bf(fmaxf(a0[r] + b0f, 0.f));
                US[row * 256 + ((wc + 16 + lr) ^ ((row & 7) << 3))] = f2bf(fmaxf(a1[r] + b1f, 0.f));
            }
        }
    }
    __syncthreads();

    // phase 8: m2 + residual -> HL
    {
        short8 w0[8], w1[8];
        const unsigned short* wp0 = m2t + (size_t)(wc + lr) * 256 + lk;
        const unsigned short* wp1 = m2t + (size_t)(wc + 16 + lr) * 256 + lk;
        #pragma unroll
        for (int kk = 0; kk < 8; ++kk) {
            w0[kk] = *(const short8*)(wp0 + kk * 32);
            w1[kk] = *(const short8*)(wp1 + kk * 32);
        }
        const float b0f = m2b[wc + lr], b1f = m2b[wc + 16 + lr];
        #pragma unroll
        for (int mt = 0; mt < 2; ++mt) {
            short8 a[8];
            #pragma unroll
            for (int kk = 0; kk < 8; ++kk) a[kk] = afrag256(US, mt * 16 + lr, kk * 32 + lk);
            f32x4 a0 = (f32x4){0.f,0.f,0.f,0.f}, a1 = (f32x4){0.f,0.f,0.f,0.f};
            #pragma unroll
            for (int kk = 0; kk < 8; ++kk) {
                a0 = __builtin_amdgcn_mfma_f32_16x16x32_bf16(a[kk], w0[kk], a0, 0, 0, 0);
                a1 = __builtin_amdgcn_mfma_f32_16x16x32_bf16(a[kk], w1[kk], a1, 0, 0, 0);
            }
            #pragma unroll
            for (int r = 0; r < 4; ++r) {
                int row = mt * 16 + mr + r;
                HL[row][wc + lr]      = a0[r] + b0f + HL[row][wc + lr];
                HL[row][wc + 16 + lr] = a1[r] + b1f + HL[row][wc + 16 + lr];
            }
        }
    }
    __syncthreads();

    // epilogue
    if (last) {
        #pragma unroll
        for (int rr = 0; rr < 4; ++rr) {
            int row = wave * 4 + rr;
            *(float4*)(outf + ((size_t)m0 + row) * 256 + lane * 4) =
                *(const float4*)&HL[row][lane * 4];
        }
    } else {
        const float4 w4 = *(const float4*)(nsw + lane * 4);
        const float4 b4 = *(const float4*)(nsb + lane * 4);
        #pragma unroll
        for (int rr = 0; rr < 4; ++rr) {
            int row = wave * 4 + rr;
            float4 v = *(const float4*)&HL[row][lane * 4];
            float s1 = v.x + v.y + v.z + v.w;
            float s2 = v.x * v.x + v.y * v.y + v.z * v.z + v.w * v.w;
            #pragma unroll
            for (int m = 32; m >= 1; m >>= 1) { s1 += __shfl_xor(s1, m); s2 += __shfl_xor(s2, m); }
            float mu_ = s1 * (1.f / 256.f);
            float rs_ = rsqrtf(s2 * (1.f / 256.f) - mu_ * mu_ + 1e-5f);
            size_t off = ((size_t)m0 + row) * 256 + lane * 4;
            *(float4*)(ping + off) = v;
            *(ull*)(sraw + off) = pack4(v.x, v.y, v.z, v.w);
            *(ull*)(lnq + off) = pack4(
                (v.x - mu_) * rs_ * w4.x + b4.x, (v.y - mu_) * rs_ * w4.y + b4.y,
                (v.z - mu_) * rs_ * w4.z + b4.z, (v.w - mu_) * rs_ * w4.w + b4.w);
        }
    }
}

// ------------------------------------------------------------------
extern "C" void kernel_launch(void* const* d_in, const int* in_sizes, int n_in,
                              void* d_out, int out_size, void* d_ws, size_t ws_size,
                              hipStream_t stream) {
    (void)in_sizes; (void)n_in; (void)ws_size; (void)out_size;
    unsigned short* wsb  = (unsigned short*)d_ws;
    unsigned short* ksb  = wsb + (1u << 20);         // K
    unsigned short* vtb  = ksb + 16777216;           // V^T
    float* ping = (float*)(vtb + 16777216);
    unsigned short* srawb = (unsigned short*)(ping + 2097152);
    unsigned short* lnqb  = srawb + 2097152;

    const unsigned short* f1t   = wsb;
    const unsigned short* f2t   = wsb + 65536;
    const unsigned short* kt    = wsb + 131072;
    const unsigned short* vwt   = wsb + 196608;
    const unsigned short* qt    = wsb + 262144;
    const unsigned short* m1t   = wsb + 327680;
    const unsigned short* m2t   = wsb + 393216;
    const unsigned short* gihb  = wsb + 458752;
    const unsigned short* ghhb  = wsb + 655360;
    const unsigned short* pos_t = wsb + 851968;
    const unsigned short* enwb  = wsb + 868352;
    const unsigned short* enbb  = wsb + 884736;

    prep_kernel<<<dim3(1760 + 1024), dim3(512), 0, stream>>>(
        (const float*)d_in[6],  (const float*)d_in[8],  (const float*)d_in[14],
        (const float*)d_in[16], (const float*)d_in[12], (const float*)d_in[26],
        (const float*)d_in[28], (const float*)d_in[18], (const float*)d_in[19],
        (const float*)d_in[2],  (const float*)d_in[3],   // posW, posb
        (const float*)d_in[4],  (const float*)d_in[5],   // enln_w, enln_b
        (const float*)d_in[30], (const float*)d_in[31],  // slots_mu, slots_sigma
        (const float*)d_in[1],                           // noise
        (const float*)d_in[22], (const float*)d_in[23],  // ns_w, ns_b
        wsb, ping, srawb, lnqb);

    enc_kernel<<<dim3(1024), dim3(512), 0, stream>>>(
        (const float*)d_in[0], pos_t, enwb, enbb,
        f1t, (const float*)d_in[7],
        f2t, (const float*)d_in[9],
        (const float*)d_in[10], (const float*)d_in[11],
        kt, (const float*)d_in[15], vwt, (const float*)d_in[17],
        ksb, vtb);

    for (int it = 0; it < 5; ++it) {
        iter_kernel<<<dim3(256), dim3(512), 0, stream>>>(
            ksb, vtb, qt, gihb, ghhb, m1t, m2t,
            (const float*)d_in[13], (const float*)d_in[20], (const float*)d_in[21],
            (const float*)d_in[24], (const float*)d_in[25],
            (const float*)d_in[27], (const float*)d_in[29],
            (const float*)d_in[22], (const float*)d_in[23],
            ping, srawb, lnqb,
            (float*)d_out, it == 4 ? 1 : 0);
    }
}